// Round 7
// baseline (645.492 us; speedup 1.0000x reference)
//
#include <hip/hip_runtime.h>
#include <math.h>

#define BB 16
#define SS 256
#define DD 41
#define LL (SS*DD)      // 10496
#define LAT 128
#define NH 4
#define NL 3
#define RSQ 0.08838834764831845f             // 1/sqrt(128)

typedef short bf16x8 __attribute__((ext_vector_type(8)));
typedef float f32x4 __attribute__((ext_vector_type(4)));
#define MFMA __builtin_amdgcn_mfma_f32_16x16x32_bf16

__device__ __forceinline__ unsigned short f2b(float f) {
    unsigned u = __builtin_bit_cast(unsigned, f);
    unsigned r = (u + 0x7FFFu + ((u >> 16) & 1u)) >> 16;
    return (unsigned short)r;
}
__device__ __forceinline__ float b2f(unsigned short h) {
    unsigned u = ((unsigned)h) << 16;
    return __builtin_bit_cast(float, u);
}

// ---------------- stable compaction (ballot/popcount scan) ----------------
__global__ __launch_bounds__(256)
void k_compact(const float* __restrict__ time_x, const float* __restrict__ value_x,
               const int* __restrict__ mask_x,
               float* __restrict__ compT, float* __restrict__ compU,
               int* __restrict__ compC, int* __restrict__ nvalid)
{
    int b = blockIdx.x, tid = threadIdx.x;
    int lane = tid & 63, w = tid >> 6;
    __shared__ int sW[4];
    __shared__ int s_base;
    if (tid == 0) s_base = 0;
    __syncthreads();
    for (int j0 = 0; j0 < LL; j0 += 256) {
        int j = j0 + tid;
        int m = mask_x[b * LL + j];
        unsigned long long bal = __ballot(m != 0);
        int pre = __popcll(bal & ((1ull << lane) - 1ull));
        if (lane == 0) sW[w] = __popcll(bal);
        __syncthreads();
        int woff = 0;
        for (int i = 0; i < w; ++i) woff += sW[i];
        int tot = sW[0] + sW[1] + sW[2] + sW[3];
        if (m) {
            int pos = s_base + woff + pre;
            compT[b * LL + pos] = time_x[b * SS + j / DD];
            compU[b * LL + pos] = value_x[b * LL + j];
            compC[b * LL + pos] = j % DD;
        }
        __syncthreads();
        if (tid == 0) s_base += tot;
        __syncthreads();
    }
    if (tid == 0) nvalid[b] = s_base;
}

// ---------------- Z init (writes f32 Z, mk, optional bf16 Zb) ----------------
template<int UZ>
__global__ __launch_bounds__(256)
void k_init(const float* __restrict__ Wi, const float* __restrict__ bi,
            const float* __restrict__ compT, const float* __restrict__ compU,
            const int* __restrict__ compC, const int* __restrict__ nvalid,
            float* __restrict__ out, unsigned short* __restrict__ Zb)
{
    int b = blockIdx.y, p0 = blockIdx.x * 8, tid = threadIdx.x;
    float* Z = out;
    float* MK = out + (size_t)BB * LL * LAT;
    int nv = nvalid[b];
    for (int s = 0; s < 2; ++s) {
        int e = s * 256 + tid;
        int r = e >> 6, k2 = (e & 63) * 2;
        int p = p0 + r;
        size_t zi = ((size_t)b * LL + p) * LAT + k2;
        float v0 = 0.f, v1 = 0.f;
        if (p < nv) {
            int c = compC[b * LL + p];
            float t = compT[b * LL + p], u = compU[b * LL + p];
            v0 = fmaxf(Wi[c * LAT + k2]     + t * Wi[41 * LAT + k2]     + u * Wi[42 * LAT + k2]     + bi[k2],     0.f);
            v1 = fmaxf(Wi[c * LAT + k2 + 1] + t * Wi[41 * LAT + k2 + 1] + u * Wi[42 * LAT + k2 + 1] + bi[k2 + 1], 0.f);
        }
        *(float2*)&Z[zi] = make_float2(v0, v1);
        if constexpr (UZ) {
            unsigned short h2[2] = {f2b(v0), f2b(v1)};
            *(unsigned*)&Zb[((size_t)b * LL + p) * LAT + k2] = *(const unsigned*)h2;
        }
        if (k2 == 0) MK[b * LL + p] = (p < nv) ? 1.f : 0.f;
    }
}

// ---------------- prep (all layers): Qh0 (f32+bf16), transposed bf16 weights ----------------
__global__ __launch_bounds__(256)
void k_prep(const float* __restrict__ I, const float* __restrict__ Wq,
            const float* __restrict__ bq,
            const float* __restrict__ Wk, const float* __restrict__ Wv,
            const float* __restrict__ Wo,
            float* __restrict__ Qh0f, unsigned short* __restrict__ Qh0b,
            unsigned short* __restrict__ WkT, unsigned short* __restrict__ WvT,
            unsigned short* __restrict__ WqT, unsigned short* __restrict__ WoT)
{
    __shared__ float srow[128];
    int blk = blockIdx.x, tid = threadIdx.x, l = blockIdx.y;
    const float* Il  = I  + (size_t)l * 16384;
    const float* Wq0 = Wq + (size_t)(l * 2 + 0) * 16384;
    const float* bq0 = bq + (size_t)(l * 2 + 0) * 128;
    const float* Wk0 = Wk + (size_t)(l * 2 + 0) * 16384;
    const float* Wv0 = Wv + (size_t)(l * 2 + 0) * 16384;
    const float* Wq1 = Wq + (size_t)(l * 2 + 1) * 16384;
    const float* Wo1 = Wo + (size_t)(l * 2 + 1) * 16384;
    if (blk < 128) {
        if (tid < 128) srow[tid] = Il[blk * 128 + tid];
        __syncthreads();
        if (tid < 128) {
            float acc = bq0[tid];
            for (int i = 0; i < 128; ++i) acc += srow[i] * Wq0[i * 128 + tid];
            Qh0f[(size_t)l * 16384 + blk * 128 + tid] = acc;
            Qh0b[(size_t)l * 16384 + blk * 128 + tid] = f2b(acc);
        }
    } else {
        const float* src = (blk == 128) ? Wk0 : (blk == 129) ? Wv0 : (blk == 130) ? Wq1 : Wo1;
        unsigned short* dst = (blk == 128) ? WkT : (blk == 129) ? WvT : (blk == 130) ? WqT : WoT;
        dst += (size_t)l * 16384;
        for (int e = tid; e < 16384; e += 256) {
            int i = e >> 7, n = e & 127;
            dst[n * 128 + i] = f2b(src[e]);
        }
    }
}

// ---------------- MAB0 flash (MFMA, swapped scores, in-register softmax) ----------------
template<int UZ>
__global__ __launch_bounds__(512, 4)
void k_flash0(const float* __restrict__ Z, const unsigned short* __restrict__ Zb,
              const unsigned short* __restrict__ Qh0b,
              const unsigned short* __restrict__ WkT, const unsigned short* __restrict__ WvT,
              const float* __restrict__ bk0, const float* __restrict__ bv0,
              const int* __restrict__ nvalid, float* __restrict__ ml,
              unsigned short* __restrict__ accp, int ks)
{
    const int chunk = blockIdx.x, b = blockIdx.y;
    const int tid = threadIdx.x, lane = tid & 63, w = tid >> 6;
    const int l16 = lane & 15, g4 = lane >> 4;
    const f32x4 fz = {0.f, 0.f, 0.f, 0.f};

    __shared__ unsigned short sZ[32 * 136];   // [kk][i]
    __shared__ unsigned short sKh[32 * 136];  // [kk][d]
    __shared__ unsigned short sVT[128 * 40];  // [d][kk]
    __shared__ unsigned short sPw[8][16 * 40];// per-wave P scratch [q][key]

    f32x4 acc[8];
    #pragma unroll
    for (int n = 0; n < 8; ++n) acc[n] = fz;
    float mreg[NH], lreg[NH];
    #pragma unroll
    for (int h = 0; h < NH; ++h) { mreg[h] = -1e30f; lreg[h] = 0.f; }

    int nv = nvalid[b];
    int c0 = (int)(((long long)chunk * nv) / ks);
    int c1 = (int)(((long long)(chunk + 1) * nv) / ks);

    float bkd = bk0[w * 16 + l16];
    float bvd = bv0[w * 16 + l16];
    unsigned short* ps = sPw[w];

    const int sr = tid >> 4, sc = (tid & 15) * 8;   // staging coords
    float4 pa, pb;        // UZ=0 prefetch regs
    uint4 pz;             // UZ=1 prefetch regs
    if (c0 < c1) {
        if constexpr (UZ) {
            pz = *(const uint4*)&Zb[((size_t)b * LL + c0 + sr) * LAT + sc];
        } else {
            const float* s = &Z[((size_t)b * LL + c0 + sr) * LAT + sc];
            pa = *(const float4*)s; pb = *(const float4*)(s + 4);
        }
    }

    for (int kt = c0; kt < c1; kt += 32) {
        int nk = min(32, c1 - kt);
        // write staged tile to LDS; rows >= nk zeroed
        if constexpr (UZ) {
            uint4 z4 = {0u, 0u, 0u, 0u};
            *(uint4*)&sZ[sr * 136 + sc] = (sr < nk) ? pz : z4;
        } else {
            bf16x8 v;
            if (sr < nk) {
                ((unsigned short*)&v)[0] = f2b(pa.x);
                ((unsigned short*)&v)[1] = f2b(pa.y);
                ((unsigned short*)&v)[2] = f2b(pa.z);
                ((unsigned short*)&v)[3] = f2b(pa.w);
                ((unsigned short*)&v)[4] = f2b(pb.x);
                ((unsigned short*)&v)[5] = f2b(pb.y);
                ((unsigned short*)&v)[6] = f2b(pb.z);
                ((unsigned short*)&v)[7] = f2b(pb.w);
            } else {
                #pragma unroll
                for (int j = 0; j < 8; ++j) ((unsigned short*)&v)[j] = 0;
            }
            *(bf16x8*)&sZ[sr * 136 + sc] = v;
        }
        __syncthreads();
        // prefetch next tile (hides under proj + heads)
        if (kt + 32 < c1) {
            if constexpr (UZ) {
                pz = *(const uint4*)&Zb[((size_t)b * LL + kt + 32 + sr) * LAT + sc];
            } else {
                const float* s = &Z[((size_t)b * LL + kt + 32 + sr) * LAT + sc];
                pa = *(const float4*)s; pb = *(const float4*)(s + 4);
            }
        }
        // KV projection: wave w -> d-cols 16w..16w+15
        {
            f32x4 ck[2] = {fz, fz}, cv[2] = {fz, fz};
            #pragma unroll
            for (int k = 0; k < 4; ++k) {
                bf16x8 a0 = *(const bf16x8*)&sZ[(l16) * 136 + k * 32 + g4 * 8];
                bf16x8 a1 = *(const bf16x8*)&sZ[(16 + l16) * 136 + k * 32 + g4 * 8];
                bf16x8 bk_ = *(const bf16x8*)&WkT[(w * 16 + l16) * 128 + k * 32 + g4 * 8];
                bf16x8 bv_ = *(const bf16x8*)&WvT[(w * 16 + l16) * 128 + k * 32 + g4 * 8];
                ck[0] = MFMA(a0, bk_, ck[0], 0, 0, 0);
                ck[1] = MFMA(a1, bk_, ck[1], 0, 0, 0);
                cv[0] = MFMA(a0, bv_, cv[0], 0, 0, 0);
                cv[1] = MFMA(a1, bv_, cv[1], 0, 0, 0);
            }
            #pragma unroll
            for (int m = 0; m < 2; ++m)
                #pragma unroll
                for (int r = 0; r < 4; ++r) {
                    int kk = m * 16 + g4 * 4 + r;
                    int d = w * 16 + l16;
                    sKh[kk * 136 + d] = f2b(ck[m][r] + bkd);
                    sVT[d * 40 + kk] = f2b(cv[m][r] + bvd);
                }
        }
        __syncthreads();
        // heads: swapped scores, per-lane softmax state for q = w*16+l16
        #pragma unroll
        for (int h = 0; h < NH; ++h) {
            bf16x8 bq = *(const bf16x8*)&Qh0b[(w * 16 + l16) * 128 + h * 32 + g4 * 8];
            f32x4 s0 = MFMA(*(const bf16x8*)&sKh[(l16) * 136 + h * 32 + g4 * 8], bq, fz, 0, 0, 0);
            f32x4 s1 = MFMA(*(const bf16x8*)&sKh[(16 + l16) * 136 + h * 32 + g4 * 8], bq, fz, 0, 0, 0);
            float sv[2][4];
            float mx = -1e30f;
            #pragma unroll
            for (int mt = 0; mt < 2; ++mt)
                #pragma unroll
                for (int r = 0; r < 4; ++r) {
                    int key = mt * 16 + g4 * 4 + r;
                    float v = (key < nk) ? ((mt ? s1[r] : s0[r]) * RSQ) : -1e30f;
                    sv[mt][r] = v;
                    mx = fmaxf(mx, v);
                }
            mx = fmaxf(mx, __shfl_xor(mx, 16));
            mx = fmaxf(mx, __shfl_xor(mx, 32));
            float mo = mreg[h];
            float mn = fmaxf(mo, mx);
            float scl = __expf(mo - mn);
            float ls = 0.f;
            unsigned short p4[2][4];
            #pragma unroll
            for (int mt = 0; mt < 2; ++mt)
                #pragma unroll
                for (int r = 0; r < 4; ++r) {
                    int key = mt * 16 + g4 * 4 + r;
                    float p = (key < nk) ? __expf(sv[mt][r] - mn) : 0.f;
                    p4[mt][r] = f2b(p);
                    ls += p;
                }
            ls += __shfl_xor(ls, 16);
            ls += __shfl_xor(ls, 32);
            mreg[h] = mn;
            lreg[h] = lreg[h] * scl + ls;
            *(uint2*)&ps[l16 * 40 + g4 * 4]      = *(const uint2*)p4[0];
            *(uint2*)&ps[l16 * 40 + 16 + g4 * 4] = *(const uint2*)p4[1];
            // rescale acc rows (q' = g4*4+r) with scale from lane q'
            float scq[4];
            #pragma unroll
            for (int r = 0; r < 4; ++r) scq[r] = __shfl(scl, g4 * 4 + r);
            #pragma unroll
            for (int nn = 0; nn < 2; ++nn)
                #pragma unroll
                for (int r = 0; r < 4; ++r) acc[2 * h + nn][r] *= scq[r];
            bf16x8 aP = *(const bf16x8*)&ps[l16 * 40 + g4 * 8];
            #pragma unroll
            for (int nn = 0; nn < 2; ++nn) {
                bf16x8 bV = *(const bf16x8*)&sVT[(h * 32 + nn * 16 + l16) * 40 + g4 * 8];
                acc[2 * h + nn] = MFMA(aP, bV, acc[2 * h + nn], 0, 0, 0);
            }
        }
    }
    // epilogue
    size_t mlbase = ((size_t)((size_t)b * ks + chunk) * NH) * 128 * 2;
    if (g4 == 0) {
        int q = w * 16 + l16;
        #pragma unroll
        for (int h = 0; h < NH; ++h) {
            ml[mlbase + ((size_t)h * 128 + q) * 2 + 0] = mreg[h];
            ml[mlbase + ((size_t)h * 128 + q) * 2 + 1] = lreg[h];
        }
    }
    size_t abase = ((size_t)((size_t)b * ks + chunk) * 128) * 128;
    #pragma unroll
    for (int n = 0; n < 8; ++n)
        #pragma unroll
        for (int r = 0; r < 4; ++r) {
            int q = w * 16 + g4 * 4 + r;
            int d = n * 16 + l16;
            accp[abase + (size_t)q * 128 + d] = f2b(acc[n][r]);
        }
}

// ---------------- fused: merge MAB0 partials -> O0 -> H -> Kh1b/Vh1Tb ----------------
__global__ __launch_bounds__(128)
void k_post0(const float* __restrict__ ml, const unsigned short* __restrict__ accp,
             const float* __restrict__ Qh0f,
             const float* __restrict__ Wo0, const float* __restrict__ bo0,
             const float* __restrict__ Wk1, const float* __restrict__ bk1,
             const float* __restrict__ Wv1, const float* __restrict__ bv1,
             unsigned short* __restrict__ Kh1b, unsigned short* __restrict__ Vh1Tb, int ks)
{
    int q = blockIdx.x, b = blockIdx.y, d = threadIdx.x, h = d >> 5;
    __shared__ float sx[128], sh2[128];
    float M = -1e30f;
    for (int c = 0; c < ks; ++c)
        M = fmaxf(M, ml[((((size_t)b * ks + c) * NH + h) * 128 + q) * 2]);
    float L = 0.f, A = 0.f;
    for (int c = 0; c < ks; ++c) {
        size_t base = ((((size_t)b * ks + c) * NH + h) * 128 + q) * 2;
        float sc = __expf(ml[base] - M);
        L += sc * ml[base + 1];
        A += sc * b2f(accp[(((size_t)b * ks + c) * 128 + q) * 128 + d]);
    }
    float o0 = Qh0f[q * 128 + d] + ((L > 0.f) ? A / L : 0.f);
    sx[d] = o0;
    __syncthreads();
    float acc = bo0[d];
    for (int i = 0; i < 128; ++i) acc += sx[i] * Wo0[i * 128 + d];
    float hv = o0 + fmaxf(acc, 0.f);
    sh2[d] = hv;
    __syncthreads();
    float ak = bk1[d], av = bv1[d];
    for (int i = 0; i < 128; ++i) {
        float x = sh2[i];
        ak += x * Wk1[i * 128 + d];
        av += x * Wv1[i * 128 + d];
    }
    Kh1b[((size_t)b * 128 + q) * 128 + d] = f2b(ak);
    Vh1Tb[((size_t)b * 128 + d) * 128 + q] = f2b(av);
}

// ---------------- MAB1 fused (MFMA, in-register softmax), 32 rows / 4 waves ----------------
template<int UZ>
__global__ __launch_bounds__(256, 5)
void k_mab1(float* __restrict__ Z, unsigned short* __restrict__ Zb,
            const unsigned short* __restrict__ Kh1b,
            const unsigned short* __restrict__ Vh1Tb,
            const unsigned short* __restrict__ WqT, const float* __restrict__ bq1,
            const unsigned short* __restrict__ WoT, const float* __restrict__ bo1,
            const int* __restrict__ nvalid, int writeZb)
{
    const int b = blockIdx.y;
    const int p0 = blockIdx.x * 32;
    const int nv = nvalid[b];
    if (p0 >= nv) return;
    const int tid = threadIdx.x, lane = tid & 63, w = tid >> 6;   // w = 0..3 = head
    const int l16 = lane & 15, g4 = lane >> 4;
    const f32x4 fz = {0.f, 0.f, 0.f, 0.f};

    __shared__ unsigned short sQh[32 * 136];      // Qh1 [q][d], becomes O in-place
    __shared__ unsigned short sU[4 * 16 * 136];   // phase1: staged Z [32][136]; phase2: per-wave P scratch

    // ---- stage Z tile -> bf16 LDS (rows >= nv are zero in source)
    {
        int r = tid >> 3, c = (tid & 7) * 16;
        if constexpr (UZ) {
            const uint4* zsrc = (const uint4*)&Zb[((size_t)b * LL + p0 + r) * LAT + c];
            *(uint4*)&sU[r * 136 + c]     = zsrc[0];
            *(uint4*)&sU[r * 136 + c + 8] = zsrc[1];
        } else {
            const float* zr = &Z[((size_t)b * LL + p0 + r) * LAT + c];
            #pragma unroll
            for (int half = 0; half < 2; ++half) {
                float4 f0 = *(const float4*)(zr + half * 8);
                float4 f1 = *(const float4*)(zr + half * 8 + 4);
                bf16x8 v;
                ((unsigned short*)&v)[0] = f2b(f0.x);
                ((unsigned short*)&v)[1] = f2b(f0.y);
                ((unsigned short*)&v)[2] = f2b(f0.z);
                ((unsigned short*)&v)[3] = f2b(f0.w);
                ((unsigned short*)&v)[4] = f2b(f1.x);
                ((unsigned short*)&v)[5] = f2b(f1.y);
                ((unsigned short*)&v)[6] = f2b(f1.z);
                ((unsigned short*)&v)[7] = f2b(f1.w);
                *(bf16x8*)&sU[r * 136 + c + half * 8] = v;
            }
        }
    }
    __syncthreads();
    // ---- Qh1 = Z @ Wq1 + bq1 ; wave w -> cols w*32..w*32+32 (2 col-tiles)
    #pragma unroll
    for (int ct = 0; ct < 2; ++ct) {
        f32x4 c2[2] = {fz, fz};
        int col = w * 32 + ct * 16 + l16;
        #pragma unroll
        for (int ks4 = 0; ks4 < 4; ++ks4) {
            bf16x8 bw = *(const bf16x8*)&WqT[col * 128 + ks4 * 32 + g4 * 8];
            #pragma unroll
            for (int mt = 0; mt < 2; ++mt) {
                bf16x8 a = *(const bf16x8*)&sU[(mt * 16 + l16) * 136 + ks4 * 32 + g4 * 8];
                c2[mt] = MFMA(a, bw, c2[mt], 0, 0, 0);
            }
        }
        float bqv = bq1[col];
        #pragma unroll
        for (int mt = 0; mt < 2; ++mt)
            #pragma unroll
            for (int r = 0; r < 4; ++r)
                sQh[(mt * 16 + g4 * 4 + r) * 136 + col] = f2b(c2[mt][r] + bqv);
    }
    __syncthreads();   // sU free -> per-wave P scratch

    unsigned short* ps = &sU[w * 16 * 136];
    const int h = w;
    f32x4 oacc[2][2];   // [qt][nn]

    #pragma unroll
    for (int qt = 0; qt < 2; ++qt) {
        // swapped scores: lane holds S[key = mt*16+g4*4+r][q = qt*16+l16]
        bf16x8 bq8 = *(const bf16x8*)&sQh[(qt * 16 + l16) * 136 + h * 32 + g4 * 8];
        f32x4 s[8];
        #pragma unroll
        for (int mt = 0; mt < 8; ++mt) {
            bf16x8 ak = *(const bf16x8*)&Kh1b[((size_t)b * 128 + mt * 16 + l16) * 128 + h * 32 + g4 * 8];
            s[mt] = MFMA(ak, bq8, fz, 0, 0, 0);
        }
        float mx = -1e30f;
        #pragma unroll
        for (int mt = 0; mt < 8; ++mt)
            #pragma unroll
            for (int r = 0; r < 4; ++r) mx = fmaxf(mx, s[mt][r]);
        mx = fmaxf(mx, __shfl_xor(mx, 16));
        mx = fmaxf(mx, __shfl_xor(mx, 32));
        float ls = 0.f;
        #pragma unroll
        for (int mt = 0; mt < 8; ++mt)
            #pragma unroll
            for (int r = 0; r < 4; ++r) {
                float p = __expf((s[mt][r] - mx) * RSQ);
                s[mt][r] = p;
                ls += p;
            }
        ls += __shfl_xor(ls, 16);
        ls += __shfl_xor(ls, 32);
        float inv = 1.f / ls;
        #pragma unroll
        for (int mt = 0; mt < 8; ++mt) {
            unsigned short p4[4];
            #pragma unroll
            for (int r = 0; r < 4; ++r) p4[r] = f2b(s[mt][r] * inv);
            *(uint2*)&ps[l16 * 136 + mt * 16 + g4 * 4] = *(const uint2*)p4;
        }
        #pragma unroll
        for (int nn = 0; nn < 2; ++nn) {
            f32x4 o = fz;
            #pragma unroll
            for (int ks4 = 0; ks4 < 4; ++ks4) {
                bf16x8 aP = *(const bf16x8*)&ps[l16 * 136 + ks4 * 32 + g4 * 8];
                bf16x8 bV = *(const bf16x8*)&Vh1Tb[((size_t)b * 128 + h * 32 + nn * 16 + l16) * 128 + ks4 * 32 + g4 * 8];
                o = MFMA(aP, bV, o, 0, 0, 0);
            }
            oacc[qt][nn] = o;
        }
    }
    // O = Qh + attn, in-place into sQh (wave-disjoint cols h*32..+32)
    #pragma unroll
    for (int qt = 0; qt < 2; ++qt)
        #pragma unroll
        for (int nn = 0; nn < 2; ++nn) {
            int col = h * 32 + nn * 16 + l16;
            #pragma unroll
            for (int r = 0; r < 4; ++r) {
                int row = qt * 16 + g4 * 4 + r;
                float val = oacc[qt][nn][r] + b2f(sQh[row * 136 + col]);
                sQh[row * 136 + col] = f2b(val);
            }
        }
    __syncthreads();
    // out = Zold + O + relu(O @ Wo1 + bo1); wave w -> cols w*32..+32; direct epilogue
    #pragma unroll
    for (int ct = 0; ct < 2; ++ct) {
        f32x4 c2[2] = {fz, fz};
        int col = w * 32 + ct * 16 + l16;
        #pragma unroll
        for (int ks4 = 0; ks4 < 4; ++ks4) {
            bf16x8 bw = *(const bf16x8*)&WoT[col * 128 + ks4 * 32 + g4 * 8];
            #pragma unroll
            for (int mt = 0; mt < 2; ++mt) {
                bf16x8 a = *(const bf16x8*)&sQh[(mt * 16 + l16) * 136 + ks4 * 32 + g4 * 8];
                c2[mt] = MFMA(a, bw, c2[mt], 0, 0, 0);
            }
        }
        float bov = bo1[col];
        #pragma unroll
        for (int mt = 0; mt < 2; ++mt)
            #pragma unroll
            for (int r = 0; r < 4; ++r) {
                int row = mt * 16 + g4 * 4 + r;
                if (p0 + row < nv) {
                    size_t zi = ((size_t)b * LL + p0 + row) * LAT + col;
                    float val = Z[zi] + b2f(sQh[row * 136 + col]) + fmaxf(c2[mt][r] + bov, 0.f);
                    Z[zi] = val;
                    if constexpr (UZ) {
                        if (writeZb) Zb[((size_t)b * LL + p0 + row) * LAT + col] = f2b(val);
                    }
                }
            }
    }
}

extern "C" void kernel_launch(void* const* d_in, const int* in_sizes, int n_in,
                              void* d_out, int out_size, void* d_ws, size_t ws_size,
                              hipStream_t stream)
{
    const float* time_x  = (const float*)d_in[0];
    const float* value_x = (const float*)d_in[1];
    const int*   mask_x  = (const int*)d_in[2];
    const float* Wi = (const float*)d_in[3];
    const float* bi = (const float*)d_in[4];
    const float* I  = (const float*)d_in[5];
    const float* Wq = (const float*)d_in[6];
    const float* bq = (const float*)d_in[7];
    const float* Wk = (const float*)d_in[8];
    const float* bk = (const float*)d_in[9];
    const float* Wv = (const float*)d_in[10];
    const float* bv = (const float*)d_in[11];
    const float* Wo = (const float*)d_in[12];
    const float* bo = (const float*)d_in[13];
    float* out = (float*)d_out;

    const size_t BL = (size_t)BB * LL;
    const size_t base_fl = 3 * BL + 64 + (size_t)NL * 16384 + 5 * (size_t)NL * 8192
                         + 2 * (size_t)BB * 8192;
    const size_t zb_fl = BL * 64 + 8192;   // bf16 Z mirror + overrun pad
    auto need = [&](int kss) -> size_t {
        // ml: BB*kss*NH*256 floats; accp: 128q*128d bf16 per (b,chunk) = 8192 floats each
        size_t fl = base_fl + (size_t)BB * kss * NH * 256 + (size_t)BB * kss * 8192 + zb_fl;
        return fl * 4;
    };
    int big, ks;
    if (ws_size >= need(64))      { big = 1; ks = 64; }
    else if (ws_size >= need(32)) { big = 1; ks = 32; }
    else                          { big = 0; ks = 16; }

    float* ws = (float*)d_ws;
    float* compT  = ws;                      ws += BL;
    float* compU  = ws;                      ws += BL;
    int*   compC  = (int*)ws;                ws += BL;
    int*   nvalid = (int*)ws;                ws += 64;
    float* Qh0f   = ws;                      ws += (size_t)NL * 16384;
    unsigned short* Qh0b  = (unsigned short*)ws;  ws += (size_t)NL * 8192;
    unsigned short* WkT   = (unsigned short*)ws;  ws += (size_t)NL * 8192;
    unsigned short* WvT   = (unsigned short*)ws;  ws += (size_t)NL * 8192;
    unsigned short* WqT   = (unsigned short*)ws;  ws += (size_t)NL * 8192;
    unsigned short* WoT   = (unsigned short*)ws;  ws += (size_t)NL * 8192;
    unsigned short* Kh1b  = (unsigned short*)ws;  ws += (size_t)BB * 8192;
    unsigned short* Vh1Tb = (unsigned short*)ws;  ws += (size_t)BB * 8192;
    float* ml     = ws;                      ws += (size_t)BB * ks * NH * 256;
    unsigned short* accp  = (unsigned short*)ws;  ws += (size_t)BB * ks * 8192;   // FIXED: was 4096
    unsigned short* Zb    = (unsigned short*)ws;  // big path only

    k_compact<<<BB, 256, 0, stream>>>(time_x, value_x, mask_x, compT, compU, compC, nvalid);
    if (big) k_init<1><<<dim3(LL / 8, BB), 256, 0, stream>>>(Wi, bi, compT, compU, compC, nvalid, out, Zb);
    else     k_init<0><<<dim3(LL / 8, BB), 256, 0, stream>>>(Wi, bi, compT, compU, compC, nvalid, out, Zb);
    k_prep<<<dim3(132, NL), 256, 0, stream>>>(I, Wq, bq, Wk, Wv, Wo,
                                              Qh0f, Qh0b, WkT, WvT, WqT, WoT);

    for (int l = 0; l < NL; ++l) {
        const float* Wo0 = Wo + (size_t)(l * 2 + 0) * 16384;
        const float* Wk1 = Wk + (size_t)(l * 2 + 1) * 16384;
        const float* Wv1 = Wv + (size_t)(l * 2 + 1) * 16384;
        const float* bk0 = bk + (l * 2 + 0) * 128;
        const float* bv0 = bv + (l * 2 + 0) * 128;
        const float* bo0 = bo + (l * 2 + 0) * 128;
        const float* bq1 = bq + (l * 2 + 1) * 128;
        const float* bk1 = bk + (l * 2 + 1) * 128;
        const float* bv1 = bv + (l * 2 + 1) * 128;
        const float* bo1 = bo + (l * 2 + 1) * 128;

        if (big)
            k_flash0<1><<<dim3(ks, BB), 512, 0, stream>>>(out, Zb, Qh0b + (size_t)l * 16384,
                                                          WkT + (size_t)l * 16384,
                                                          WvT + (size_t)l * 16384,
                                                          bk0, bv0, nvalid, ml, accp, ks);
        else
            k_flash0<0><<<dim3(ks, BB), 512, 0, stream>>>(out, Zb, Qh0b + (size_t)l * 16384,
                                                          WkT + (size_t)l * 16384,
                                                          WvT + (size_t)l * 16384,
                                                          bk0, bv0, nvalid, ml, accp, ks);
        k_post0<<<dim3(128, BB), 128, 0, stream>>>(ml, accp, Qh0f + (size_t)l * 16384,
                                                   Wo0, bo0, Wk1, bk1, Wv1, bv1, Kh1b, Vh1Tb, ks);
        int wzb = (l < NL - 1) ? 1 : 0;
        if (big)
            k_mab1<1><<<dim3(LL / 32, BB), 256, 0, stream>>>(out, Zb, Kh1b, Vh1Tb,
                                                             WqT + (size_t)l * 16384, bq1,
                                                             WoT + (size_t)l * 16384, bo1, nvalid, wzb);
        else
            k_mab1<0><<<dim3(LL / 32, BB), 256, 0, stream>>>(out, Zb, Kh1b, Vh1Tb,
                                                             WqT + (size_t)l * 16384, bq1,
                                                             WoT + (size_t)l * 16384, bo1, nvalid, wzb);
    }
}

// Round 8
// 629.989 us; speedup vs baseline: 1.0246x; 1.0246x over previous
//
#include <hip/hip_runtime.h>
#include <math.h>

#define BB 16
#define SS 256
#define DD 41
#define LL (SS*DD)      // 10496
#define LAT 128
#define NH 4
#define NL 3
#define RSQ 0.08838834764831845f             // 1/sqrt(128)

typedef short bf16x8 __attribute__((ext_vector_type(8)));
typedef float f32x4 __attribute__((ext_vector_type(4)));
#define MFMA __builtin_amdgcn_mfma_f32_16x16x32_bf16

__device__ __forceinline__ unsigned short f2b(float f) {
    unsigned u = __builtin_bit_cast(unsigned, f);
    unsigned r = (u + 0x7FFFu + ((u >> 16) & 1u)) >> 16;
    return (unsigned short)r;
}
__device__ __forceinline__ float b2f(unsigned short h) {
    unsigned u = ((unsigned)h) << 16;
    return __builtin_bit_cast(float, u);
}

// ---------------- stable compaction (ballot/popcount scan) ----------------
__global__ __launch_bounds__(256)
void k_compact(const float* __restrict__ time_x, const float* __restrict__ value_x,
               const int* __restrict__ mask_x,
               float* __restrict__ compT, float* __restrict__ compU,
               int* __restrict__ compC, int* __restrict__ nvalid)
{
    int b = blockIdx.x, tid = threadIdx.x;
    int lane = tid & 63, w = tid >> 6;
    __shared__ int sW[4];
    __shared__ int s_base;
    if (tid == 0) s_base = 0;
    __syncthreads();
    for (int j0 = 0; j0 < LL; j0 += 256) {
        int j = j0 + tid;
        int m = mask_x[b * LL + j];
        unsigned long long bal = __ballot(m != 0);
        int pre = __popcll(bal & ((1ull << lane) - 1ull));
        if (lane == 0) sW[w] = __popcll(bal);
        __syncthreads();
        int woff = 0;
        for (int i = 0; i < w; ++i) woff += sW[i];
        int tot = sW[0] + sW[1] + sW[2] + sW[3];
        if (m) {
            int pos = s_base + woff + pre;
            compT[b * LL + pos] = time_x[b * SS + j / DD];
            compU[b * LL + pos] = value_x[b * LL + j];
            compC[b * LL + pos] = j % DD;
        }
        __syncthreads();
        if (tid == 0) s_base += tot;
        __syncthreads();
    }
    if (tid == 0) nvalid[b] = s_base;
}

// ---------------- Z init (writes f32 Z, mk, optional bf16 Zb) ----------------
template<int UZ>
__global__ __launch_bounds__(256)
void k_init(const float* __restrict__ Wi, const float* __restrict__ bi,
            const float* __restrict__ compT, const float* __restrict__ compU,
            const int* __restrict__ compC, const int* __restrict__ nvalid,
            float* __restrict__ out, unsigned short* __restrict__ Zb)
{
    int b = blockIdx.y, p0 = blockIdx.x * 8, tid = threadIdx.x;
    float* Z = out;
    float* MK = out + (size_t)BB * LL * LAT;
    int nv = nvalid[b];
    for (int s = 0; s < 2; ++s) {
        int e = s * 256 + tid;
        int r = e >> 6, k2 = (e & 63) * 2;
        int p = p0 + r;
        size_t zi = ((size_t)b * LL + p) * LAT + k2;
        float v0 = 0.f, v1 = 0.f;
        if (p < nv) {
            int c = compC[b * LL + p];
            float t = compT[b * LL + p], u = compU[b * LL + p];
            v0 = fmaxf(Wi[c * LAT + k2]     + t * Wi[41 * LAT + k2]     + u * Wi[42 * LAT + k2]     + bi[k2],     0.f);
            v1 = fmaxf(Wi[c * LAT + k2 + 1] + t * Wi[41 * LAT + k2 + 1] + u * Wi[42 * LAT + k2 + 1] + bi[k2 + 1], 0.f);
        }
        *(float2*)&Z[zi] = make_float2(v0, v1);
        if constexpr (UZ) {
            unsigned short h2[2] = {f2b(v0), f2b(v1)};
            *(unsigned*)&Zb[((size_t)b * LL + p) * LAT + k2] = *(const unsigned*)h2;
        }
        if (k2 == 0) MK[b * LL + p] = (p < nv) ? 1.f : 0.f;
    }
}

// ---------------- prep (all layers): Qh0 (f32+bf16), transposed bf16 weights ----------------
__global__ __launch_bounds__(256)
void k_prep(const float* __restrict__ I, const float* __restrict__ Wq,
            const float* __restrict__ bq,
            const float* __restrict__ Wk, const float* __restrict__ Wv,
            const float* __restrict__ Wo,
            float* __restrict__ Qh0f, unsigned short* __restrict__ Qh0b,
            unsigned short* __restrict__ WkT, unsigned short* __restrict__ WvT,
            unsigned short* __restrict__ WqT, unsigned short* __restrict__ WoT)
{
    __shared__ float srow[128];
    int blk = blockIdx.x, tid = threadIdx.x, l = blockIdx.y;
    const float* Il  = I  + (size_t)l * 16384;
    const float* Wq0 = Wq + (size_t)(l * 2 + 0) * 16384;
    const float* bq0 = bq + (size_t)(l * 2 + 0) * 128;
    const float* Wk0 = Wk + (size_t)(l * 2 + 0) * 16384;
    const float* Wv0 = Wv + (size_t)(l * 2 + 0) * 16384;
    const float* Wq1 = Wq + (size_t)(l * 2 + 1) * 16384;
    const float* Wo1 = Wo + (size_t)(l * 2 + 1) * 16384;
    if (blk < 128) {
        if (tid < 128) srow[tid] = Il[blk * 128 + tid];
        __syncthreads();
        if (tid < 128) {
            float acc = bq0[tid];
            for (int i = 0; i < 128; ++i) acc += srow[i] * Wq0[i * 128 + tid];
            Qh0f[(size_t)l * 16384 + blk * 128 + tid] = acc;
            Qh0b[(size_t)l * 16384 + blk * 128 + tid] = f2b(acc);
        }
    } else {
        const float* src = (blk == 128) ? Wk0 : (blk == 129) ? Wv0 : (blk == 130) ? Wq1 : Wo1;
        unsigned short* dst = (blk == 128) ? WkT : (blk == 129) ? WvT : (blk == 130) ? WqT : WoT;
        dst += (size_t)l * 16384;
        for (int e = tid; e < 16384; e += 256) {
            int i = e >> 7, n = e & 127;
            dst[n * 128 + i] = f2b(src[e]);
        }
    }
}

// ---------------- MAB0 flash (MFMA, swapped scores, reg-hoisted weights) ----------------
template<int UZ>
__global__ __launch_bounds__(512, 4)
void k_flash0(const float* __restrict__ Z, const unsigned short* __restrict__ Zb,
              const unsigned short* __restrict__ Qh0b,
              const unsigned short* __restrict__ WkT, const unsigned short* __restrict__ WvT,
              const float* __restrict__ bk0, const float* __restrict__ bv0,
              const int* __restrict__ nvalid, float* __restrict__ ml,
              unsigned short* __restrict__ accp, int ks)
{
    const int chunk = blockIdx.x, b = blockIdx.y;
    const int tid = threadIdx.x, lane = tid & 63, w = tid >> 6;
    const int l16 = lane & 15, g4 = lane >> 4;
    const f32x4 fz = {0.f, 0.f, 0.f, 0.f};

    __shared__ unsigned short sZ[32 * 136];   // [kk][i]
    __shared__ unsigned short sKh[32 * 136];  // [kk][d]
    __shared__ unsigned short sVT[128 * 40];  // [d][kk]
    __shared__ unsigned short sPw[8][16 * 40];// per-wave P scratch [q][key]

    // hoisted invariant fragments (reused every K-tile)
    bf16x8 wkf[4], wvf[4], qf[NH];
    #pragma unroll
    for (int k = 0; k < 4; ++k) {
        wkf[k] = *(const bf16x8*)&WkT[(w * 16 + l16) * 128 + k * 32 + g4 * 8];
        wvf[k] = *(const bf16x8*)&WvT[(w * 16 + l16) * 128 + k * 32 + g4 * 8];
    }
    #pragma unroll
    for (int h = 0; h < NH; ++h)
        qf[h] = *(const bf16x8*)&Qh0b[(w * 16 + l16) * 128 + h * 32 + g4 * 8];

    f32x4 acc[8];
    #pragma unroll
    for (int n = 0; n < 8; ++n) acc[n] = fz;
    float mreg[NH], lreg[NH];
    #pragma unroll
    for (int h = 0; h < NH; ++h) { mreg[h] = -1e30f; lreg[h] = 0.f; }

    int nv = nvalid[b];
    int c0 = (int)(((long long)chunk * nv) / ks);
    int c1 = (int)(((long long)(chunk + 1) * nv) / ks);

    float bkd = bk0[w * 16 + l16];
    float bvd = bv0[w * 16 + l16];
    unsigned short* ps = sPw[w];

    const int sr = tid >> 4, sc = (tid & 15) * 8;   // staging coords
    float4 pa, pb;        // UZ=0 prefetch regs
    uint4 pz;             // UZ=1 prefetch regs
    if (c0 < c1) {
        if constexpr (UZ) {
            pz = *(const uint4*)&Zb[((size_t)b * LL + c0 + sr) * LAT + sc];
        } else {
            const float* s = &Z[((size_t)b * LL + c0 + sr) * LAT + sc];
            pa = *(const float4*)s; pb = *(const float4*)(s + 4);
        }
    }

    for (int kt = c0; kt < c1; kt += 32) {
        int nk = min(32, c1 - kt);
        // write staged tile to LDS; rows >= nk zeroed
        if constexpr (UZ) {
            uint4 z4 = {0u, 0u, 0u, 0u};
            *(uint4*)&sZ[sr * 136 + sc] = (sr < nk) ? pz : z4;
        } else {
            bf16x8 v;
            if (sr < nk) {
                ((unsigned short*)&v)[0] = f2b(pa.x);
                ((unsigned short*)&v)[1] = f2b(pa.y);
                ((unsigned short*)&v)[2] = f2b(pa.z);
                ((unsigned short*)&v)[3] = f2b(pa.w);
                ((unsigned short*)&v)[4] = f2b(pb.x);
                ((unsigned short*)&v)[5] = f2b(pb.y);
                ((unsigned short*)&v)[6] = f2b(pb.z);
                ((unsigned short*)&v)[7] = f2b(pb.w);
            } else {
                #pragma unroll
                for (int j = 0; j < 8; ++j) ((unsigned short*)&v)[j] = 0;
            }
            *(bf16x8*)&sZ[sr * 136 + sc] = v;
        }
        __syncthreads();
        // prefetch next tile (hides under proj + heads)
        if (kt + 32 < c1) {
            if constexpr (UZ) {
                pz = *(const uint4*)&Zb[((size_t)b * LL + kt + 32 + sr) * LAT + sc];
            } else {
                const float* s = &Z[((size_t)b * LL + kt + 32 + sr) * LAT + sc];
                pa = *(const float4*)s; pb = *(const float4*)(s + 4);
            }
        }
        // KV projection: wave w -> d-cols 16w..16w+15 (weights in regs)
        {
            f32x4 ck[2] = {fz, fz}, cv[2] = {fz, fz};
            #pragma unroll
            for (int k = 0; k < 4; ++k) {
                bf16x8 a0 = *(const bf16x8*)&sZ[(l16) * 136 + k * 32 + g4 * 8];
                bf16x8 a1 = *(const bf16x8*)&sZ[(16 + l16) * 136 + k * 32 + g4 * 8];
                ck[0] = MFMA(a0, wkf[k], ck[0], 0, 0, 0);
                ck[1] = MFMA(a1, wkf[k], ck[1], 0, 0, 0);
                cv[0] = MFMA(a0, wvf[k], cv[0], 0, 0, 0);
                cv[1] = MFMA(a1, wvf[k], cv[1], 0, 0, 0);
            }
            #pragma unroll
            for (int m = 0; m < 2; ++m)
                #pragma unroll
                for (int r = 0; r < 4; ++r) {
                    int kk = m * 16 + g4 * 4 + r;
                    int d = w * 16 + l16;
                    sKh[kk * 136 + d] = f2b(ck[m][r] + bkd);
                    sVT[d * 40 + kk] = f2b(cv[m][r] + bvd);
                }
        }
        __syncthreads();
        // heads: swapped scores, per-lane softmax state for q = w*16+l16
        #pragma unroll
        for (int h = 0; h < NH; ++h) {
            f32x4 s0 = MFMA(*(const bf16x8*)&sKh[(l16) * 136 + h * 32 + g4 * 8], qf[h], fz, 0, 0, 0);
            f32x4 s1 = MFMA(*(const bf16x8*)&sKh[(16 + l16) * 136 + h * 32 + g4 * 8], qf[h], fz, 0, 0, 0);
            float sv[2][4];
            float mx = -1e30f;
            #pragma unroll
            for (int mt = 0; mt < 2; ++mt)
                #pragma unroll
                for (int r = 0; r < 4; ++r) {
                    int key = mt * 16 + g4 * 4 + r;
                    float v = (key < nk) ? ((mt ? s1[r] : s0[r]) * RSQ) : -1e30f;
                    sv[mt][r] = v;
                    mx = fmaxf(mx, v);
                }
            mx = fmaxf(mx, __shfl_xor(mx, 16));
            mx = fmaxf(mx, __shfl_xor(mx, 32));
            float mo = mreg[h];
            float mn = fmaxf(mo, mx);
            float scl = __expf(mo - mn);
            float ls = 0.f;
            unsigned short p4[2][4];
            #pragma unroll
            for (int mt = 0; mt < 2; ++mt)
                #pragma unroll
                for (int r = 0; r < 4; ++r) {
                    int key = mt * 16 + g4 * 4 + r;
                    float p = (key < nk) ? __expf(sv[mt][r] - mn) : 0.f;
                    p4[mt][r] = f2b(p);
                    ls += p;
                }
            ls += __shfl_xor(ls, 16);
            ls += __shfl_xor(ls, 32);
            mreg[h] = mn;
            lreg[h] = lreg[h] * scl + ls;
            *(uint2*)&ps[l16 * 40 + g4 * 4]      = *(const uint2*)p4[0];
            *(uint2*)&ps[l16 * 40 + 16 + g4 * 4] = *(const uint2*)p4[1];
            // rescale acc rows (q' = g4*4+r) with scale from lane q'
            float scq[4];
            #pragma unroll
            for (int r = 0; r < 4; ++r) scq[r] = __shfl(scl, g4 * 4 + r);
            #pragma unroll
            for (int nn = 0; nn < 2; ++nn)
                #pragma unroll
                for (int r = 0; r < 4; ++r) acc[2 * h + nn][r] *= scq[r];
            bf16x8 aP = *(const bf16x8*)&ps[l16 * 40 + g4 * 8];
            #pragma unroll
            for (int nn = 0; nn < 2; ++nn) {
                bf16x8 bV = *(const bf16x8*)&sVT[(h * 32 + nn * 16 + l16) * 40 + g4 * 8];
                acc[2 * h + nn] = MFMA(aP, bV, acc[2 * h + nn], 0, 0, 0);
            }
        }
    }
    // epilogue
    size_t mlbase = ((size_t)((size_t)b * ks + chunk) * NH) * 128 * 2;
    if (g4 == 0) {
        int q = w * 16 + l16;
        #pragma unroll
        for (int h = 0; h < NH; ++h) {
            ml[mlbase + ((size_t)h * 128 + q) * 2 + 0] = mreg[h];
            ml[mlbase + ((size_t)h * 128 + q) * 2 + 1] = lreg[h];
        }
    }
    size_t abase = ((size_t)((size_t)b * ks + chunk) * 128) * 128;
    #pragma unroll
    for (int n = 0; n < 8; ++n)
        #pragma unroll
        for (int r = 0; r < 4; ++r) {
            int q = w * 16 + g4 * 4 + r;
            int d = n * 16 + l16;
            accp[abase + (size_t)q * 128 + d] = f2b(acc[n][r]);
        }
}

// ---------------- fused: merge MAB0 partials -> O0 -> H -> Kh1b/Vh1Tb ----------------
__global__ __launch_bounds__(128)
void k_post0(const float* __restrict__ ml, const unsigned short* __restrict__ accp,
             const float* __restrict__ Qh0f,
             const float* __restrict__ Wo0, const float* __restrict__ bo0,
             const float* __restrict__ Wk1, const float* __restrict__ bk1,
             const float* __restrict__ Wv1, const float* __restrict__ bv1,
             unsigned short* __restrict__ Kh1b, unsigned short* __restrict__ Vh1Tb, int ks)
{
    int q = blockIdx.x, b = blockIdx.y, d = threadIdx.x, h = d >> 5;
    __shared__ float sx[128], sh2[128];
    float M = -1e30f;
    for (int c = 0; c < ks; ++c)
        M = fmaxf(M, ml[((((size_t)b * ks + c) * NH + h) * 128 + q) * 2]);
    float L = 0.f, A = 0.f;
    for (int c = 0; c < ks; ++c) {
        size_t base = ((((size_t)b * ks + c) * NH + h) * 128 + q) * 2;
        float sc = __expf(ml[base] - M);
        L += sc * ml[base + 1];
        A += sc * b2f(accp[(((size_t)b * ks + c) * 128 + q) * 128 + d]);
    }
    float o0 = Qh0f[q * 128 + d] + ((L > 0.f) ? A / L : 0.f);
    sx[d] = o0;
    __syncthreads();
    float acc = bo0[d];
    for (int i = 0; i < 128; ++i) acc += sx[i] * Wo0[i * 128 + d];
    float hv = o0 + fmaxf(acc, 0.f);
    sh2[d] = hv;
    __syncthreads();
    float ak = bk1[d], av = bv1[d];
    for (int i = 0; i < 128; ++i) {
        float x = sh2[i];
        ak += x * Wk1[i * 128 + d];
        av += x * Wv1[i * 128 + d];
    }
    Kh1b[((size_t)b * 128 + q) * 128 + d] = f2b(ak);
    Vh1Tb[((size_t)b * 128 + d) * 128 + q] = f2b(av);
}

// ---------------- MAB1 fused (MFMA, in-reg softmax, reg-hoisted K/V/res) ----------------
template<int UZ>
__global__ __launch_bounds__(256, 4)
void k_mab1(float* __restrict__ Z, unsigned short* __restrict__ Zb,
            const unsigned short* __restrict__ Kh1b,
            const unsigned short* __restrict__ Vh1Tb,
            const unsigned short* __restrict__ WqT, const float* __restrict__ bq1,
            const unsigned short* __restrict__ WoT, const float* __restrict__ bo1,
            const int* __restrict__ nvalid, int writeZb)
{
    const int b = blockIdx.y;
    const int p0 = blockIdx.x * 32;
    const int nv = nvalid[b];
    if (p0 >= nv) return;
    const int tid = threadIdx.x, lane = tid & 63, w = tid >> 6;   // w = 0..3 = head
    const int l16 = lane & 15, g4 = lane >> 4;
    const int h = w;
    const f32x4 fz = {0.f, 0.f, 0.f, 0.f};

    __shared__ unsigned short sQh[32 * 136];      // Qh1 [q][d], becomes O in-place
    __shared__ unsigned short sU[4 * 16 * 136];   // phase1: staged Z [32][136]; phase2: per-wave P scratch

    // ---- issue all independent global loads first (latency overlaps)
    // (1) staged Z tile
    const int str = tid >> 3, stc = (tid & 7) * 16;
    uint4 pz0, pz1;          // UZ=1
    float4 pf[4];            // UZ=0
    if constexpr (UZ) {
        const uint4* zsrc = (const uint4*)&Zb[((size_t)b * LL + p0 + str) * LAT + stc];
        pz0 = zsrc[0]; pz1 = zsrc[1];
    } else {
        const float* zr = &Z[((size_t)b * LL + p0 + str) * LAT + stc];
        pf[0] = *(const float4*)(zr);     pf[1] = *(const float4*)(zr + 4);
        pf[2] = *(const float4*)(zr + 8); pf[3] = *(const float4*)(zr + 12);
    }
    // (2) K / V fragments for this wave's head (invariant across qt)
    bf16x8 kf[8], vf[2][4];
    #pragma unroll
    for (int mt = 0; mt < 8; ++mt)
        kf[mt] = *(const bf16x8*)&Kh1b[((size_t)b * 128 + mt * 16 + l16) * 128 + h * 32 + g4 * 8];
    #pragma unroll
    for (int nn = 0; nn < 2; ++nn)
        #pragma unroll
        for (int ks4 = 0; ks4 < 4; ++ks4)
            vf[nn][ks4] = *(const bf16x8*)&Vh1Tb[((size_t)b * 128 + h * 32 + nn * 16 + l16) * 128 + ks4 * 32 + g4 * 8];
    // (3) residual Z values for epilogue (cols w*32..+32)
    float zres[2][2][4];
    #pragma unroll
    for (int ct = 0; ct < 2; ++ct)
        #pragma unroll
        for (int mt = 0; mt < 2; ++mt)
            #pragma unroll
            for (int r = 0; r < 4; ++r)
                zres[ct][mt][r] = Z[((size_t)b * LL + p0 + mt * 16 + g4 * 4 + r) * LAT + w * 32 + ct * 16 + l16];

    // ---- write staged tile to LDS
    if constexpr (UZ) {
        *(uint4*)&sU[str * 136 + stc]     = pz0;
        *(uint4*)&sU[str * 136 + stc + 8] = pz1;
    } else {
        #pragma unroll
        for (int half = 0; half < 2; ++half) {
            float4 f0 = pf[half * 2], f1 = pf[half * 2 + 1];
            bf16x8 v;
            ((unsigned short*)&v)[0] = f2b(f0.x);
            ((unsigned short*)&v)[1] = f2b(f0.y);
            ((unsigned short*)&v)[2] = f2b(f0.z);
            ((unsigned short*)&v)[3] = f2b(f0.w);
            ((unsigned short*)&v)[4] = f2b(f1.x);
            ((unsigned short*)&v)[5] = f2b(f1.y);
            ((unsigned short*)&v)[6] = f2b(f1.z);
            ((unsigned short*)&v)[7] = f2b(f1.w);
            *(bf16x8*)&sU[str * 136 + stc + half * 8] = v;
        }
    }
    __syncthreads();
    // ---- Qh1 = Z @ Wq1 + bq1 ; wave w -> cols w*32..w*32+32 (2 col-tiles)
    #pragma unroll
    for (int ct = 0; ct < 2; ++ct) {
        f32x4 c2[2] = {fz, fz};
        int col = w * 32 + ct * 16 + l16;
        #pragma unroll
        for (int ks4 = 0; ks4 < 4; ++ks4) {
            bf16x8 bw = *(const bf16x8*)&WqT[col * 128 + ks4 * 32 + g4 * 8];
            #pragma unroll
            for (int mt = 0; mt < 2; ++mt) {
                bf16x8 a = *(const bf16x8*)&sU[(mt * 16 + l16) * 136 + ks4 * 32 + g4 * 8];
                c2[mt] = MFMA(a, bw, c2[mt], 0, 0, 0);
            }
        }
        float bqv = bq1[col];
        #pragma unroll
        for (int mt = 0; mt < 2; ++mt)
            #pragma unroll
            for (int r = 0; r < 4; ++r)
                sQh[(mt * 16 + g4 * 4 + r) * 136 + col] = f2b(c2[mt][r] + bqv);
    }
    __syncthreads();   // sU free -> per-wave P scratch

    unsigned short* ps = &sU[w * 16 * 136];
    f32x4 oacc[2][2];   // [qt][nn]

    #pragma unroll
    for (int qt = 0; qt < 2; ++qt) {
        // swapped scores: lane holds S[key = mt*16+g4*4+r][q = qt*16+l16]
        bf16x8 bq8 = *(const bf16x8*)&sQh[(qt * 16 + l16) * 136 + h * 32 + g4 * 8];
        f32x4 s[8];
        #pragma unroll
        for (int mt = 0; mt < 8; ++mt)
            s[mt] = MFMA(kf[mt], bq8, fz, 0, 0, 0);
        float mx = -1e30f;
        #pragma unroll
        for (int mt = 0; mt < 8; ++mt)
            #pragma unroll
            for (int r = 0; r < 4; ++r) mx = fmaxf(mx, s[mt][r]);
        mx = fmaxf(mx, __shfl_xor(mx, 16));
        mx = fmaxf(mx, __shfl_xor(mx, 32));
        float ls = 0.f;
        #pragma unroll
        for (int mt = 0; mt < 8; ++mt)
            #pragma unroll
            for (int r = 0; r < 4; ++r) {
                float p = __expf((s[mt][r] - mx) * RSQ);
                s[mt][r] = p;
                ls += p;
            }
        ls += __shfl_xor(ls, 16);
        ls += __shfl_xor(ls, 32);
        float inv = 1.f / ls;
        #pragma unroll
        for (int mt = 0; mt < 8; ++mt) {
            unsigned short p4[4];
            #pragma unroll
            for (int r = 0; r < 4; ++r) p4[r] = f2b(s[mt][r] * inv);
            *(uint2*)&ps[l16 * 136 + mt * 16 + g4 * 4] = *(const uint2*)p4;
        }
        #pragma unroll
        for (int nn = 0; nn < 2; ++nn) {
            f32x4 o = fz;
            #pragma unroll
            for (int ks4 = 0; ks4 < 4; ++ks4) {
                bf16x8 aP = *(const bf16x8*)&ps[l16 * 136 + ks4 * 32 + g4 * 8];
                o = MFMA(aP, vf[nn][ks4], o, 0, 0, 0);
            }
            oacc[qt][nn] = o;
        }
    }
    // O = Qh + attn, in-place into sQh (wave-disjoint cols h*32..+32)
    #pragma unroll
    for (int qt = 0; qt < 2; ++qt)
        #pragma unroll
        for (int nn = 0; nn < 2; ++nn) {
            int col = h * 32 + nn * 16 + l16;
            #pragma unroll
            for (int r = 0; r < 4; ++r) {
                int row = qt * 16 + g4 * 4 + r;
                float val = oacc[qt][nn][r] + b2f(sQh[row * 136 + col]);
                sQh[row * 136 + col] = f2b(val);
            }
        }
    __syncthreads();
    // out = Zres + O + relu(O @ Wo1 + bo1); wave w -> cols w*32..+32
    #pragma unroll
    for (int ct = 0; ct < 2; ++ct) {
        f32x4 c2[2] = {fz, fz};
        int col = w * 32 + ct * 16 + l16;
        #pragma unroll
        for (int ks4 = 0; ks4 < 4; ++ks4) {
            bf16x8 bw = *(const bf16x8*)&WoT[col * 128 + ks4 * 32 + g4 * 8];
            #pragma unroll
            for (int mt = 0; mt < 2; ++mt) {
                bf16x8 a = *(const bf16x8*)&sQh[(mt * 16 + l16) * 136 + ks4 * 32 + g4 * 8];
                c2[mt] = MFMA(a, bw, c2[mt], 0, 0, 0);
            }
        }
        float bov = bo1[col];
        #pragma unroll
        for (int mt = 0; mt < 2; ++mt)
            #pragma unroll
            for (int r = 0; r < 4; ++r) {
                int row = mt * 16 + g4 * 4 + r;
                if (p0 + row < nv) {
                    size_t zi = ((size_t)b * LL + p0 + row) * LAT + col;
                    float val = zres[ct][mt][r] + b2f(sQh[row * 136 + col]) + fmaxf(c2[mt][r] + bov, 0.f);
                    Z[zi] = val;
                    if constexpr (UZ) {
                        if (writeZb) Zb[((size_t)b * LL + p0 + row) * LAT + col] = f2b(val);
                    }
                }
            }
    }
}

extern "C" void kernel_launch(void* const* d_in, const int* in_sizes, int n_in,
                              void* d_out, int out_size, void* d_ws, size_t ws_size,
                              hipStream_t stream)
{
    const float* time_x  = (const float*)d_in[0];
    const float* value_x = (const float*)d_in[1];
    const int*   mask_x  = (const int*)d_in[2];
    const float* Wi = (const float*)d_in[3];
    const float* bi = (const float*)d_in[4];
    const float* I  = (const float*)d_in[5];
    const float* Wq = (const float*)d_in[6];
    const float* bq = (const float*)d_in[7];
    const float* Wk = (const float*)d_in[8];
    const float* bk = (const float*)d_in[9];
    const float* Wv = (const float*)d_in[10];
    const float* bv = (const float*)d_in[11];
    const float* Wo = (const float*)d_in[12];
    const float* bo = (const float*)d_in[13];
    float* out = (float*)d_out;

    const size_t BL = (size_t)BB * LL;
    const size_t base_fl = 3 * BL + 64 + (size_t)NL * 16384 + 5 * (size_t)NL * 8192
                         + 2 * (size_t)BB * 8192;
    const size_t zb_fl = BL * 64 + 8192;   // bf16 Z mirror + overrun pad
    auto need = [&](int kss) -> size_t {
        size_t fl = base_fl + (size_t)BB * kss * NH * 256 + (size_t)BB * kss * 8192 + zb_fl;
        return fl * 4;
    };
    int big, ks;
    if (ws_size >= need(32))      { big = 1; ks = 32; }
    else                          { big = 0; ks = 16; }

    float* ws = (float*)d_ws;
    float* compT  = ws;                      ws += BL;
    float* compU  = ws;                      ws += BL;
    int*   compC  = (int*)ws;                ws += BL;
    int*   nvalid = (int*)ws;                ws += 64;
    float* Qh0f   = ws;                      ws += (size_t)NL * 16384;
    unsigned short* Qh0b  = (unsigned short*)ws;  ws += (size_t)NL * 8192;
    unsigned short* WkT   = (unsigned short*)ws;  ws += (size_t)NL * 8192;
    unsigned short* WvT   = (unsigned short*)ws;  ws += (size_t)NL * 8192;
    unsigned short* WqT   = (unsigned short*)ws;  ws += (size_t)NL * 8192;
    unsigned short* WoT   = (unsigned short*)ws;  ws += (size_t)NL * 8192;
    unsigned short* Kh1b  = (unsigned short*)ws;  ws += (size_t)BB * 8192;
    unsigned short* Vh1Tb = (unsigned short*)ws;  ws += (size_t)BB * 8192;
    float* ml     = ws;                      ws += (size_t)BB * ks * NH * 256;
    unsigned short* accp  = (unsigned short*)ws;  ws += (size_t)BB * ks * 8192;
    unsigned short* Zb    = (unsigned short*)ws;  // big path only

    k_compact<<<BB, 256, 0, stream>>>(time_x, value_x, mask_x, compT, compU, compC, nvalid);
    if (big) k_init<1><<<dim3(LL / 8, BB), 256, 0, stream>>>(Wi, bi, compT, compU, compC, nvalid, out, Zb);
    else     k_init<0><<<dim3(LL / 8, BB), 256, 0, stream>>>(Wi, bi, compT, compU, compC, nvalid, out, Zb);
    k_prep<<<dim3(132, NL), 256, 0, stream>>>(I, Wq, bq, Wk, Wv, Wo,
                                              Qh0f, Qh0b, WkT, WvT, WqT, WoT);

    for (int l = 0; l < NL; ++l) {
        const float* Wo0 = Wo + (size_t)(l * 2 + 0) * 16384;
        const float* Wk1 = Wk + (size_t)(l * 2 + 1) * 16384;
        const float* Wv1 = Wv + (size_t)(l * 2 + 1) * 16384;
        const float* bk0 = bk + (l * 2 + 0) * 128;
        const float* bv0 = bv + (l * 2 + 0) * 128;
        const float* bo0 = bo + (l * 2 + 0) * 128;
        const float* bq1 = bq + (l * 2 + 1) * 128;
        const float* bk1 = bk + (l * 2 + 1) * 128;
        const float* bv1 = bv + (l * 2 + 1) * 128;
        const float* bo1 = bo + (l * 2 + 1) * 128;

        if (big)
            k_flash0<1><<<dim3(ks, BB), 512, 0, stream>>>(out, Zb, Qh0b + (size_t)l * 16384,
                                                          WkT + (size_t)l * 16384,
                                                          WvT + (size_t)l * 16384,
                                                          bk0, bv0, nvalid, ml, accp, ks);
        else
            k_flash0<0><<<dim3(ks, BB), 512, 0, stream>>>(out, Zb, Qh0b + (size_t)l * 16384,
                                                          WkT + (size_t)l * 16384,
                                                          WvT + (size_t)l * 16384,
                                                          bk0, bv0, nvalid, ml, accp, ks);
        k_post0<<<dim3(128, BB), 128, 0, stream>>>(ml, accp, Qh0f + (size_t)l * 16384,
                                                   Wo0, bo0, Wk1, bk1, Wv1, bv1, Kh1b, Vh1Tb, ks);
        int wzb = (l < NL - 1) ? 1 : 0;
        if (big)
            k_mab1<1><<<dim3(LL / 32, BB), 256, 0, stream>>>(out, Zb, Kh1b, Vh1Tb,
                                                             WqT + (size_t)l * 16384, bq1,
                                                             WoT + (size_t)l * 16384, bo1, nvalid, wzb);
        else
            k_mab1<0><<<dim3(LL / 32, BB), 256, 0, stream>>>(out, Zb, Kh1b, Vh1Tb,
                                                             WqT + (size_t)l * 16384, bq1,
                                                             WoT + (size_t)l * 16384, bo1, nvalid, wzb);
    }
}

// Round 9
// 497.695 us; speedup vs baseline: 1.2970x; 1.2658x over previous
//
#include <hip/hip_runtime.h>
#include <math.h>

#define BB 16
#define SS 256
#define DD 41
#define LL (SS*DD)      // 10496
#define LAT 128
#define NH 4
#define NL 3
#define MAB1_NC 32      // persistent chunks per batch for MAB1
#define RSQ 0.08838834764831845f             // 1/sqrt(128)

typedef short bf16x8 __attribute__((ext_vector_type(8)));
typedef float f32x4 __attribute__((ext_vector_type(4)));
#define MFMA __builtin_amdgcn_mfma_f32_16x16x32_bf16

__device__ __forceinline__ unsigned short f2b(float f) {
    unsigned u = __builtin_bit_cast(unsigned, f);
    unsigned r = (u + 0x7FFFu + ((u >> 16) & 1u)) >> 16;
    return (unsigned short)r;
}
__device__ __forceinline__ float b2f(unsigned short h) {
    unsigned u = ((unsigned)h) << 16;
    return __builtin_bit_cast(float, u);
}

// ---------------- stable compaction (ballot/popcount scan) ----------------
__global__ __launch_bounds__(256)
void k_compact(const float* __restrict__ time_x, const float* __restrict__ value_x,
               const int* __restrict__ mask_x,
               float* __restrict__ compT, float* __restrict__ compU,
               int* __restrict__ compC, int* __restrict__ nvalid)
{
    int b = blockIdx.x, tid = threadIdx.x;
    int lane = tid & 63, w = tid >> 6;
    __shared__ int sW[4];
    __shared__ int s_base;
    if (tid == 0) s_base = 0;
    __syncthreads();
    for (int j0 = 0; j0 < LL; j0 += 256) {
        int j = j0 + tid;
        int m = mask_x[b * LL + j];
        unsigned long long bal = __ballot(m != 0);
        int pre = __popcll(bal & ((1ull << lane) - 1ull));
        if (lane == 0) sW[w] = __popcll(bal);
        __syncthreads();
        int woff = 0;
        for (int i = 0; i < w; ++i) woff += sW[i];
        int tot = sW[0] + sW[1] + sW[2] + sW[3];
        if (m) {
            int pos = s_base + woff + pre;
            compT[b * LL + pos] = time_x[b * SS + j / DD];
            compU[b * LL + pos] = value_x[b * LL + j];
            compC[b * LL + pos] = j % DD;
        }
        __syncthreads();
        if (tid == 0) s_base += tot;
        __syncthreads();
    }
    if (tid == 0) nvalid[b] = s_base;
}

// ---------------- Z init (writes f32 Z, mk, optional bf16 Zb) ----------------
template<int UZ>
__global__ __launch_bounds__(256)
void k_init(const float* __restrict__ Wi, const float* __restrict__ bi,
            const float* __restrict__ compT, const float* __restrict__ compU,
            const int* __restrict__ compC, const int* __restrict__ nvalid,
            float* __restrict__ out, unsigned short* __restrict__ Zb)
{
    int b = blockIdx.y, p0 = blockIdx.x * 8, tid = threadIdx.x;
    float* Z = out;
    float* MK = out + (size_t)BB * LL * LAT;
    int nv = nvalid[b];
    for (int s = 0; s < 2; ++s) {
        int e = s * 256 + tid;
        int r = e >> 6, k2 = (e & 63) * 2;
        int p = p0 + r;
        size_t zi = ((size_t)b * LL + p) * LAT + k2;
        float v0 = 0.f, v1 = 0.f;
        if (p < nv) {
            int c = compC[b * LL + p];
            float t = compT[b * LL + p], u = compU[b * LL + p];
            v0 = fmaxf(Wi[c * LAT + k2]     + t * Wi[41 * LAT + k2]     + u * Wi[42 * LAT + k2]     + bi[k2],     0.f);
            v1 = fmaxf(Wi[c * LAT + k2 + 1] + t * Wi[41 * LAT + k2 + 1] + u * Wi[42 * LAT + k2 + 1] + bi[k2 + 1], 0.f);
        }
        *(float2*)&Z[zi] = make_float2(v0, v1);
        if constexpr (UZ) {
            unsigned short h2[2] = {f2b(v0), f2b(v1)};
            *(unsigned*)&Zb[((size_t)b * LL + p) * LAT + k2] = *(const unsigned*)h2;
        }
        if (k2 == 0) MK[b * LL + p] = (p < nv) ? 1.f : 0.f;
    }
}

// ---------------- prep (all layers): Qh0 (f32+bf16), transposed bf16 weights ----------------
__global__ __launch_bounds__(256)
void k_prep(const float* __restrict__ I, const float* __restrict__ Wq,
            const float* __restrict__ bq,
            const float* __restrict__ Wk, const float* __restrict__ Wv,
            const float* __restrict__ Wo,
            float* __restrict__ Qh0f, unsigned short* __restrict__ Qh0b,
            unsigned short* __restrict__ WkT, unsigned short* __restrict__ WvT,
            unsigned short* __restrict__ WqT, unsigned short* __restrict__ WoT)
{
    __shared__ float srow[128];
    int blk = blockIdx.x, tid = threadIdx.x, l = blockIdx.y;
    const float* Il  = I  + (size_t)l * 16384;
    const float* Wq0 = Wq + (size_t)(l * 2 + 0) * 16384;
    const float* bq0 = bq + (size_t)(l * 2 + 0) * 128;
    const float* Wk0 = Wk + (size_t)(l * 2 + 0) * 16384;
    const float* Wv0 = Wv + (size_t)(l * 2 + 0) * 16384;
    const float* Wq1 = Wq + (size_t)(l * 2 + 1) * 16384;
    const float* Wo1 = Wo + (size_t)(l * 2 + 1) * 16384;
    if (blk < 128) {
        if (tid < 128) srow[tid] = Il[blk * 128 + tid];
        __syncthreads();
        if (tid < 128) {
            float acc = bq0[tid];
            for (int i = 0; i < 128; ++i) acc += srow[i] * Wq0[i * 128 + tid];
            Qh0f[(size_t)l * 16384 + blk * 128 + tid] = acc;
            Qh0b[(size_t)l * 16384 + blk * 128 + tid] = f2b(acc);
        }
    } else {
        const float* src = (blk == 128) ? Wk0 : (blk == 129) ? Wv0 : (blk == 130) ? Wq1 : Wo1;
        unsigned short* dst = (blk == 128) ? WkT : (blk == 129) ? WvT : (blk == 130) ? WqT : WoT;
        dst += (size_t)l * 16384;
        for (int e = tid; e < 16384; e += 256) {
            int i = e >> 7, n = e & 127;
            dst[n * 128 + i] = f2b(src[e]);
        }
    }
}

// ---------------- MAB0 flash (MFMA, swapped scores, reg-hoisted weights) ----------------
template<int UZ>
__global__ __launch_bounds__(512, 4)
void k_flash0(const float* __restrict__ Z, const unsigned short* __restrict__ Zb,
              const unsigned short* __restrict__ Qh0b,
              const unsigned short* __restrict__ WkT, const unsigned short* __restrict__ WvT,
              const float* __restrict__ bk0, const float* __restrict__ bv0,
              const int* __restrict__ nvalid, float* __restrict__ ml,
              unsigned short* __restrict__ accp, int ks)
{
    const int chunk = blockIdx.x, b = blockIdx.y;
    const int tid = threadIdx.x, lane = tid & 63, w = tid >> 6;
    const int l16 = lane & 15, g4 = lane >> 4;
    const f32x4 fz = {0.f, 0.f, 0.f, 0.f};

    __shared__ unsigned short sZ[32 * 136];   // [kk][i]
    __shared__ unsigned short sKh[32 * 136];  // [kk][d]
    __shared__ unsigned short sVT[128 * 40];  // [d][kk]
    __shared__ unsigned short sPw[8][16 * 40];// per-wave P scratch [q][key]

    // hoisted invariant fragments (reused every K-tile)
    bf16x8 wkf[4], wvf[4], qf[NH];
    #pragma unroll
    for (int k = 0; k < 4; ++k) {
        wkf[k] = *(const bf16x8*)&WkT[(w * 16 + l16) * 128 + k * 32 + g4 * 8];
        wvf[k] = *(const bf16x8*)&WvT[(w * 16 + l16) * 128 + k * 32 + g4 * 8];
    }
    #pragma unroll
    for (int h = 0; h < NH; ++h)
        qf[h] = *(const bf16x8*)&Qh0b[(w * 16 + l16) * 128 + h * 32 + g4 * 8];

    f32x4 acc[8];
    #pragma unroll
    for (int n = 0; n < 8; ++n) acc[n] = fz;
    float mreg[NH], lreg[NH];
    #pragma unroll
    for (int h = 0; h < NH; ++h) { mreg[h] = -1e30f; lreg[h] = 0.f; }

    int nv = nvalid[b];
    int c0 = (int)(((long long)chunk * nv) / ks);
    int c1 = (int)(((long long)(chunk + 1) * nv) / ks);

    float bkd = bk0[w * 16 + l16];
    float bvd = bv0[w * 16 + l16];
    unsigned short* ps = sPw[w];

    const int sr = tid >> 4, sc = (tid & 15) * 8;   // staging coords
    float4 pa, pb;        // UZ=0 prefetch regs
    uint4 pz;             // UZ=1 prefetch regs
    if (c0 < c1) {
        if constexpr (UZ) {
            pz = *(const uint4*)&Zb[((size_t)b * LL + c0 + sr) * LAT + sc];
        } else {
            const float* s = &Z[((size_t)b * LL + c0 + sr) * LAT + sc];
            pa = *(const float4*)s; pb = *(const float4*)(s + 4);
        }
    }

    for (int kt = c0; kt < c1; kt += 32) {
        int nk = min(32, c1 - kt);
        // write staged tile to LDS; rows >= nk zeroed
        if constexpr (UZ) {
            uint4 z4 = {0u, 0u, 0u, 0u};
            *(uint4*)&sZ[sr * 136 + sc] = (sr < nk) ? pz : z4;
        } else {
            bf16x8 v;
            if (sr < nk) {
                ((unsigned short*)&v)[0] = f2b(pa.x);
                ((unsigned short*)&v)[1] = f2b(pa.y);
                ((unsigned short*)&v)[2] = f2b(pa.z);
                ((unsigned short*)&v)[3] = f2b(pa.w);
                ((unsigned short*)&v)[4] = f2b(pb.x);
                ((unsigned short*)&v)[5] = f2b(pb.y);
                ((unsigned short*)&v)[6] = f2b(pb.z);
                ((unsigned short*)&v)[7] = f2b(pb.w);
            } else {
                #pragma unroll
                for (int j = 0; j < 8; ++j) ((unsigned short*)&v)[j] = 0;
            }
            *(bf16x8*)&sZ[sr * 136 + sc] = v;
        }
        __syncthreads();
        // prefetch next tile (hides under proj + heads)
        if (kt + 32 < c1) {
            if constexpr (UZ) {
                pz = *(const uint4*)&Zb[((size_t)b * LL + kt + 32 + sr) * LAT + sc];
            } else {
                const float* s = &Z[((size_t)b * LL + kt + 32 + sr) * LAT + sc];
                pa = *(const float4*)s; pb = *(const float4*)(s + 4);
            }
        }
        // KV projection: wave w -> d-cols 16w..16w+15 (weights in regs)
        {
            f32x4 ck[2] = {fz, fz}, cv[2] = {fz, fz};
            #pragma unroll
            for (int k = 0; k < 4; ++k) {
                bf16x8 a0 = *(const bf16x8*)&sZ[(l16) * 136 + k * 32 + g4 * 8];
                bf16x8 a1 = *(const bf16x8*)&sZ[(16 + l16) * 136 + k * 32 + g4 * 8];
                ck[0] = MFMA(a0, wkf[k], ck[0], 0, 0, 0);
                ck[1] = MFMA(a1, wkf[k], ck[1], 0, 0, 0);
                cv[0] = MFMA(a0, wvf[k], cv[0], 0, 0, 0);
                cv[1] = MFMA(a1, wvf[k], cv[1], 0, 0, 0);
            }
            #pragma unroll
            for (int m = 0; m < 2; ++m)
                #pragma unroll
                for (int r = 0; r < 4; ++r) {
                    int kk = m * 16 + g4 * 4 + r;
                    int d = w * 16 + l16;
                    sKh[kk * 136 + d] = f2b(ck[m][r] + bkd);
                    sVT[d * 40 + kk] = f2b(cv[m][r] + bvd);
                }
        }
        __syncthreads();
        // heads: swapped scores, per-lane softmax state for q = w*16+l16
        #pragma unroll
        for (int h = 0; h < NH; ++h) {
            f32x4 s0 = MFMA(*(const bf16x8*)&sKh[(l16) * 136 + h * 32 + g4 * 8], qf[h], fz, 0, 0, 0);
            f32x4 s1 = MFMA(*(const bf16x8*)&sKh[(16 + l16) * 136 + h * 32 + g4 * 8], qf[h], fz, 0, 0, 0);
            float sv[2][4];
            float mx = -1e30f;
            #pragma unroll
            for (int mt = 0; mt < 2; ++mt)
                #pragma unroll
                for (int r = 0; r < 4; ++r) {
                    int key = mt * 16 + g4 * 4 + r;
                    float v = (key < nk) ? ((mt ? s1[r] : s0[r]) * RSQ) : -1e30f;
                    sv[mt][r] = v;
                    mx = fmaxf(mx, v);
                }
            mx = fmaxf(mx, __shfl_xor(mx, 16));
            mx = fmaxf(mx, __shfl_xor(mx, 32));
            float mo = mreg[h];
            float mn = fmaxf(mo, mx);
            float scl = __expf(mo - mn);
            float ls = 0.f;
            unsigned short p4[2][4];
            #pragma unroll
            for (int mt = 0; mt < 2; ++mt)
                #pragma unroll
                for (int r = 0; r < 4; ++r) {
                    int key = mt * 16 + g4 * 4 + r;
                    float p = (key < nk) ? __expf(sv[mt][r] - mn) : 0.f;
                    p4[mt][r] = f2b(p);
                    ls += p;
                }
            ls += __shfl_xor(ls, 16);
            ls += __shfl_xor(ls, 32);
            mreg[h] = mn;
            lreg[h] = lreg[h] * scl + ls;
            *(uint2*)&ps[l16 * 40 + g4 * 4]      = *(const uint2*)p4[0];
            *(uint2*)&ps[l16 * 40 + 16 + g4 * 4] = *(const uint2*)p4[1];
            // rescale acc rows (q' = g4*4+r) with scale from lane q'
            float scq[4];
            #pragma unroll
            for (int r = 0; r < 4; ++r) scq[r] = __shfl(scl, g4 * 4 + r);
            #pragma unroll
            for (int nn = 0; nn < 2; ++nn)
                #pragma unroll
                for (int r = 0; r < 4; ++r) acc[2 * h + nn][r] *= scq[r];
            bf16x8 aP = *(const bf16x8*)&ps[l16 * 40 + g4 * 8];
            #pragma unroll
            for (int nn = 0; nn < 2; ++nn) {
                bf16x8 bV = *(const bf16x8*)&sVT[(h * 32 + nn * 16 + l16) * 40 + g4 * 8];
                acc[2 * h + nn] = MFMA(aP, bV, acc[2 * h + nn], 0, 0, 0);
            }
        }
    }
    // epilogue
    size_t mlbase = ((size_t)((size_t)b * ks + chunk) * NH) * 128 * 2;
    if (g4 == 0) {
        int q = w * 16 + l16;
        #pragma unroll
        for (int h = 0; h < NH; ++h) {
            ml[mlbase + ((size_t)h * 128 + q) * 2 + 0] = mreg[h];
            ml[mlbase + ((size_t)h * 128 + q) * 2 + 1] = lreg[h];
        }
    }
    size_t abase = ((size_t)((size_t)b * ks + chunk) * 128) * 128;
    #pragma unroll
    for (int n = 0; n < 8; ++n)
        #pragma unroll
        for (int r = 0; r < 4; ++r) {
            int q = w * 16 + g4 * 4 + r;
            int d = n * 16 + l16;
            accp[abase + (size_t)q * 128 + d] = f2b(acc[n][r]);
        }
}

// ---------------- fused: merge MAB0 partials -> O0 -> H -> Kh1b/Vh1Tb ----------------
__global__ __launch_bounds__(128)
void k_post0(const float* __restrict__ ml, const unsigned short* __restrict__ accp,
             const float* __restrict__ Qh0f,
             const float* __restrict__ Wo0, const float* __restrict__ bo0,
             const float* __restrict__ Wk1, const float* __restrict__ bk1,
             const float* __restrict__ Wv1, const float* __restrict__ bv1,
             unsigned short* __restrict__ Kh1b, unsigned short* __restrict__ Vh1Tb, int ks)
{
    int q = blockIdx.x, b = blockIdx.y, d = threadIdx.x, h = d >> 5;
    __shared__ float sx[128], sh2[128];
    float M = -1e30f;
    for (int c = 0; c < ks; ++c)
        M = fmaxf(M, ml[((((size_t)b * ks + c) * NH + h) * 128 + q) * 2]);
    float L = 0.f, A = 0.f;
    for (int c = 0; c < ks; ++c) {
        size_t base = ((((size_t)b * ks + c) * NH + h) * 128 + q) * 2;
        float sc = __expf(ml[base] - M);
        L += sc * ml[base + 1];
        A += sc * b2f(accp[(((size_t)b * ks + c) * 128 + q) * 128 + d]);
    }
    float o0 = Qh0f[q * 128 + d] + ((L > 0.f) ? A / L : 0.f);
    sx[d] = o0;
    __syncthreads();
    float acc = bo0[d];
    for (int i = 0; i < 128; ++i) acc += sx[i] * Wo0[i * 128 + d];
    float hv = o0 + fmaxf(acc, 0.f);
    sh2[d] = hv;
    __syncthreads();
    float ak = bk1[d], av = bv1[d];
    for (int i = 0; i < 128; ++i) {
        float x = sh2[i];
        ak += x * Wk1[i * 128 + d];
        av += x * Wv1[i * 128 + d];
    }
    Kh1b[((size_t)b * 128 + q) * 128 + d] = f2b(ak);
    Vh1Tb[((size_t)b * 128 + d) * 128 + q] = f2b(av);
}

// ---------------- MAB1 persistent-chunk (MFMA, in-reg softmax, resident K/V/W) ----------------
template<int UZ>
__global__ __launch_bounds__(256, 2)
void k_mab1(float* __restrict__ Z, unsigned short* __restrict__ Zb,
            const unsigned short* __restrict__ Kh1b,
            const unsigned short* __restrict__ Vh1Tb,
            const unsigned short* __restrict__ WqT, const float* __restrict__ bq1,
            const unsigned short* __restrict__ WoT, const float* __restrict__ bo1,
            const int* __restrict__ nvalid, int writeZb)
{
    const int b = blockIdx.y, chunk = blockIdx.x;
    const int tid = threadIdx.x, lane = tid & 63, w = tid >> 6;   // w = 0..3 = head
    const int l16 = lane & 15, g4 = lane >> 4;
    const int h = w;
    const f32x4 fz = {0.f, 0.f, 0.f, 0.f};

    __shared__ unsigned short sZ[2][32 * 136];    // double-buffered staged Z
    __shared__ unsigned short sQh[32 * 136];      // Qh1 [q][d], becomes O in-place
    __shared__ unsigned short sP[4][16 * 136];    // per-wave P scratch

    const int nv = nvalid[b];
    int c0 = (int)(((long long)chunk * nv) / MAB1_NC);
    int c1 = (int)(((long long)(chunk + 1) * nv) / MAB1_NC);

    // ---- hoist block-invariant operands into registers (read once) ----
    bf16x8 kf[8], vf[2][4], wqf[2][4], wof[2][4];
    #pragma unroll
    for (int mt = 0; mt < 8; ++mt)
        kf[mt] = *(const bf16x8*)&Kh1b[((size_t)b * 128 + mt * 16 + l16) * 128 + h * 32 + g4 * 8];
    #pragma unroll
    for (int nn = 0; nn < 2; ++nn)
        #pragma unroll
        for (int k4 = 0; k4 < 4; ++k4)
            vf[nn][k4] = *(const bf16x8*)&Vh1Tb[((size_t)b * 128 + h * 32 + nn * 16 + l16) * 128 + k4 * 32 + g4 * 8];
    #pragma unroll
    for (int ct = 0; ct < 2; ++ct) {
        int col = w * 32 + ct * 16 + l16;
        #pragma unroll
        for (int k4 = 0; k4 < 4; ++k4) {
            wqf[ct][k4] = *(const bf16x8*)&WqT[col * 128 + k4 * 32 + g4 * 8];
            wof[ct][k4] = *(const bf16x8*)&WoT[col * 128 + k4 * 32 + g4 * 8];
        }
    }
    float bqv[2], bov[2];
    #pragma unroll
    for (int ct = 0; ct < 2; ++ct) {
        bqv[ct] = bq1[w * 32 + ct * 16 + l16];
        bov[ct] = bo1[w * 32 + ct * 16 + l16];
    }

    const int str = tid >> 3, stc = (tid & 7) * 16;   // staging coords (32 rows x 8x16 cols)
    uint4 pz0, pz1;          // UZ=1 prefetch
    float4 pf[4];            // UZ=0 prefetch
    const float4 f4z = {0.f, 0.f, 0.f, 0.f};
    const uint4 u4z = {0u, 0u, 0u, 0u};

    // preload first tile
    if (c0 < c1) {
        bool okr = (c0 + str < c1);
        if constexpr (UZ) {
            if (okr) {
                const uint4* zsrc = (const uint4*)&Zb[((size_t)b * LL + c0 + str) * LAT + stc];
                pz0 = zsrc[0]; pz1 = zsrc[1];
            } else { pz0 = u4z; pz1 = u4z; }
        } else {
            if (okr) {
                const float* zr = &Z[((size_t)b * LL + c0 + str) * LAT + stc];
                pf[0] = *(const float4*)(zr);     pf[1] = *(const float4*)(zr + 4);
                pf[2] = *(const float4*)(zr + 8); pf[3] = *(const float4*)(zr + 12);
            } else { pf[0] = pf[1] = pf[2] = pf[3] = f4z; }
        }
    }

    int cur = 0;
    for (int kt = c0; kt < c1; kt += 32) {
        int nk = min(32, c1 - kt);
        unsigned short* zb_ = sZ[cur];
        // write prefetched regs -> sZ[cur]
        if constexpr (UZ) {
            *(uint4*)&zb_[str * 136 + stc]     = pz0;
            *(uint4*)&zb_[str * 136 + stc + 8] = pz1;
        } else {
            #pragma unroll
            for (int half = 0; half < 2; ++half) {
                float4 f0 = pf[half * 2], f1 = pf[half * 2 + 1];
                bf16x8 v;
                ((unsigned short*)&v)[0] = f2b(f0.x);
                ((unsigned short*)&v)[1] = f2b(f0.y);
                ((unsigned short*)&v)[2] = f2b(f0.z);
                ((unsigned short*)&v)[3] = f2b(f0.w);
                ((unsigned short*)&v)[4] = f2b(f1.x);
                ((unsigned short*)&v)[5] = f2b(f1.y);
                ((unsigned short*)&v)[6] = f2b(f1.z);
                ((unsigned short*)&v)[7] = f2b(f1.w);
                *(bf16x8*)&zb_[str * 136 + stc + half * 8] = v;
            }
        }
        __syncthreads();
        // issue prefetch for next tile (in flight across compute)
        if (kt + 32 < c1) {
            bool okr = (kt + 32 + str < c1);
            if constexpr (UZ) {
                if (okr) {
                    const uint4* zsrc = (const uint4*)&Zb[((size_t)b * LL + kt + 32 + str) * LAT + stc];
                    pz0 = zsrc[0]; pz1 = zsrc[1];
                } else { pz0 = u4z; pz1 = u4z; }
            } else {
                if (okr) {
                    const float* zr = &Z[((size_t)b * LL + kt + 32 + str) * LAT + stc];
                    pf[0] = *(const float4*)(zr);     pf[1] = *(const float4*)(zr + 4);
                    pf[2] = *(const float4*)(zr + 8); pf[3] = *(const float4*)(zr + 12);
                } else { pf[0] = pf[1] = pf[2] = pf[3] = f4z; }
            }
        }
        // ---- Qh1 = Z @ Wq1 + bq1 ; wave w -> cols w*32..+32 (resident weights)
        #pragma unroll
        for (int ct = 0; ct < 2; ++ct) {
            f32x4 c2[2] = {fz, fz};
            int col = w * 32 + ct * 16 + l16;
            #pragma unroll
            for (int k4 = 0; k4 < 4; ++k4) {
                #pragma unroll
                for (int mt = 0; mt < 2; ++mt) {
                    bf16x8 a = *(const bf16x8*)&zb_[(mt * 16 + l16) * 136 + k4 * 32 + g4 * 8];
                    c2[mt] = MFMA(a, wqf[ct][k4], c2[mt], 0, 0, 0);
                }
            }
            #pragma unroll
            for (int mt = 0; mt < 2; ++mt)
                #pragma unroll
                for (int r = 0; r < 4; ++r)
                    sQh[(mt * 16 + g4 * 4 + r) * 136 + col] = f2b(c2[mt][r] + bqv[ct]);
        }
        // no barrier: attn reads only this wave's own sQh cols
        unsigned short* ps = sP[w];
        #pragma unroll
        for (int qt = 0; qt < 2; ++qt) {
            bf16x8 bq8 = *(const bf16x8*)&sQh[(qt * 16 + l16) * 136 + h * 32 + g4 * 8];
            f32x4 s[8];
            #pragma unroll
            for (int mt = 0; mt < 8; ++mt)
                s[mt] = MFMA(kf[mt], bq8, fz, 0, 0, 0);
            float mx = -1e30f;
            #pragma unroll
            for (int mt = 0; mt < 8; ++mt)
                #pragma unroll
                for (int r = 0; r < 4; ++r) mx = fmaxf(mx, s[mt][r]);
            mx = fmaxf(mx, __shfl_xor(mx, 16));
            mx = fmaxf(mx, __shfl_xor(mx, 32));
            float ls = 0.f;
            #pragma unroll
            for (int mt = 0; mt < 8; ++mt)
                #pragma unroll
                for (int r = 0; r < 4; ++r) {
                    float p = __expf((s[mt][r] - mx) * RSQ);
                    s[mt][r] = p;
                    ls += p;
                }
            ls += __shfl_xor(ls, 16);
            ls += __shfl_xor(ls, 32);
            float inv = 1.f / ls;
            #pragma unroll
            for (int mt = 0; mt < 8; ++mt) {
                unsigned short p4[4];
                #pragma unroll
                for (int r = 0; r < 4; ++r) p4[r] = f2b(s[mt][r] * inv);
                *(uint2*)&ps[l16 * 136 + mt * 16 + g4 * 4] = *(const uint2*)p4;
            }
            #pragma unroll
            for (int nn = 0; nn < 2; ++nn) {
                f32x4 o = fz;
                #pragma unroll
                for (int k4 = 0; k4 < 4; ++k4) {
                    bf16x8 aP = *(const bf16x8*)&ps[l16 * 136 + k4 * 32 + g4 * 8];
                    o = MFMA(aP, vf[nn][k4], o, 0, 0, 0);
                }
                // O = Qh + attn, in place (own cols, own rows qt*16..)
                int col = h * 32 + nn * 16 + l16;
                #pragma unroll
                for (int r = 0; r < 4; ++r) {
                    int row = qt * 16 + g4 * 4 + r;
                    float val = o[r] + b2f(sQh[row * 136 + col]);
                    sQh[row * 136 + col] = f2b(val);
                }
            }
        }
        __syncthreads();
        // ---- out = Zres + O + relu(O @ Wo1 + bo1); wave w -> cols w*32..+32
        #pragma unroll
        for (int ct = 0; ct < 2; ++ct) {
            f32x4 c2[2] = {fz, fz};
            int col = w * 32 + ct * 16 + l16;
            #pragma unroll
            for (int k4 = 0; k4 < 4; ++k4) {
                #pragma unroll
                for (int mt = 0; mt < 2; ++mt) {
                    bf16x8 a = *(const bf16x8*)&sQh[(mt * 16 + l16) * 136 + k4 * 32 + g4 * 8];
                    c2[mt] = MFMA(a, wof[ct][k4], c2[mt], 0, 0, 0);
                }
            }
            #pragma unroll
            for (int mt = 0; mt < 2; ++mt)
                #pragma unroll
                for (int r = 0; r < 4; ++r) {
                    int row = mt * 16 + g4 * 4 + r;
                    if (row < nk) {
                        size_t zi = ((size_t)b * LL + kt + row) * LAT + col;
                        float val = Z[zi] + b2f(sQh[row * 136 + col]) + fmaxf(c2[mt][r] + bov[ct], 0.f);
                        Z[zi] = val;
                        if constexpr (UZ) {
                            if (writeZb) Zb[((size_t)b * LL + kt + row) * LAT + col] = f2b(val);
                        }
                    }
                }
        }
        cur ^= 1;
    }
}

extern "C" void kernel_launch(void* const* d_in, const int* in_sizes, int n_in,
                              void* d_out, int out_size, void* d_ws, size_t ws_size,
                              hipStream_t stream)
{
    const float* time_x  = (const float*)d_in[0];
    const float* value_x = (const float*)d_in[1];
    const int*   mask_x  = (const int*)d_in[2];
    const float* Wi = (const float*)d_in[3];
    const float* bi = (const float*)d_in[4];
    const float* I  = (const float*)d_in[5];
    const float* Wq = (const float*)d_in[6];
    const float* bq = (const float*)d_in[7];
    const float* Wk = (const float*)d_in[8];
    const float* bk = (const float*)d_in[9];
    const float* Wv = (const float*)d_in[10];
    const float* bv = (const float*)d_in[11];
    const float* Wo = (const float*)d_in[12];
    const float* bo = (const float*)d_in[13];
    float* out = (float*)d_out;

    const size_t BL = (size_t)BB * LL;
    const size_t base_fl = 3 * BL + 64 + (size_t)NL * 16384 + 5 * (size_t)NL * 8192
                         + 2 * (size_t)BB * 8192;
    const size_t zb_fl = BL * 64 + 8192;   // bf16 Z mirror + overrun pad
    auto need = [&](int kss) -> size_t {
        size_t fl = base_fl + (size_t)BB * kss * NH * 256 + (size_t)BB * kss * 8192 + zb_fl;
        return fl * 4;
    };
    int big, ks;
    if (ws_size >= need(32))      { big = 1; ks = 32; }
    else                          { big = 0; ks = 16; }

    float* ws = (float*)d_ws;
    float* compT  = ws;                      ws += BL;
    float* compU  = ws;                      ws += BL;
    int*   compC  = (int*)ws;                ws += BL;
    int*   nvalid = (int*)ws;                ws += 64;
    float* Qh0f   = ws;                      ws += (size_t)NL * 16384;
    unsigned short* Qh0b  = (unsigned short*)ws;  ws += (size_t)NL * 8192;
    unsigned short* WkT   = (unsigned short*)ws;  ws += (size_t)NL * 8192;
    unsigned short* WvT   = (unsigned short*)ws;  ws += (size_t)NL * 8192;
    unsigned short* WqT   = (unsigned short*)ws;  ws += (size_t)NL * 8192;
    unsigned short* WoT   = (unsigned short*)ws;  ws += (size_t)NL * 8192;
    unsigned short* Kh1b  = (unsigned short*)ws;  ws += (size_t)BB * 8192;
    unsigned short* Vh1Tb = (unsigned short*)ws;  ws += (size_t)BB * 8192;
    float* ml     = ws;                      ws += (size_t)BB * ks * NH * 256;
    unsigned short* accp  = (unsigned short*)ws;  ws += (size_t)BB * ks * 8192;
    unsigned short* Zb    = (unsigned short*)ws;  // big path only

    k_compact<<<BB, 256, 0, stream>>>(time_x, value_x, mask_x, compT, compU, compC, nvalid);
    if (big) k_init<1><<<dim3(LL / 8, BB), 256, 0, stream>>>(Wi, bi, compT, compU, compC, nvalid, out, Zb);
    else     k_init<0><<<dim3(LL / 8, BB), 256, 0, stream>>>(Wi, bi, compT, compU, compC, nvalid, out, Zb);
    k_prep<<<dim3(132, NL), 256, 0, stream>>>(I, Wq, bq, Wk, Wv, Wo,
                                              Qh0f, Qh0b, WkT, WvT, WqT, WoT);

    for (int l = 0; l < NL; ++l) {
        const float* Wo0 = Wo + (size_t)(l * 2 + 0) * 16384;
        const float* Wk1 = Wk + (size_t)(l * 2 + 1) * 16384;
        const float* Wv1 = Wv + (size_t)(l * 2 + 1) * 16384;
        const float* bk0 = bk + (l * 2 + 0) * 128;
        const float* bv0 = bv + (l * 2 + 0) * 128;
        const float* bo0 = bo + (l * 2 + 0) * 128;
        const float* bq1 = bq + (l * 2 + 1) * 128;
        const float* bk1 = bk + (l * 2 + 1) * 128;
        const float* bv1 = bv + (l * 2 + 1) * 128;
        const float* bo1 = bo + (l * 2 + 1) * 128;

        if (big)
            k_flash0<1><<<dim3(ks, BB), 512, 0, stream>>>(out, Zb, Qh0b + (size_t)l * 16384,
                                                          WkT + (size_t)l * 16384,
                                                          WvT + (size_t)l * 16384,
                                                          bk0, bv0, nvalid, ml, accp, ks);
        else
            k_flash0<0><<<dim3(ks, BB), 512, 0, stream>>>(out, Zb, Qh0b + (size_t)l * 16384,
                                                          WkT + (size_t)l * 16384,
                                                          WvT + (size_t)l * 16384,
                                                          bk0, bv0, nvalid, ml, accp, ks);
        k_post0<<<dim3(128, BB), 128, 0, stream>>>(ml, accp, Qh0f + (size_t)l * 16384,
                                                   Wo0, bo0, Wk1, bk1, Wv1, bv1, Kh1b, Vh1Tb, ks);
        int wzb = (l < NL - 1) ? 1 : 0;
        if (big)
            k_mab1<1><<<dim3(MAB1_NC, BB), 256, 0, stream>>>(out, Zb, Kh1b, Vh1Tb,
                                                             WqT + (size_t)l * 16384, bq1,
                                                             WoT + (size_t)l * 16384, bo1, nvalid, wzb);
        else
            k_mab1<0><<<dim3(MAB1_NC, BB), 256, 0, stream>>>(out, Zb, Kh1b, Vh1Tb,
                                                             WqT + (size_t)l * 16384, bq1,
                                                             WoT + (size_t)l * 16384, bo1, nvalid, wzb);
    }
}

// Round 10
// 485.565 us; speedup vs baseline: 1.3294x; 1.0250x over previous
//
#include <hip/hip_runtime.h>
#include <math.h>

#define BB 16
#define SS 256
#define DD 41
#define LL (SS*DD)      // 10496
#define LAT 128
#define NH 4
#define NL 3
#define MAB1_NC 32      // persistent chunks per batch for MAB1
#define PSC 0.12751743f // log2(e)/sqrt(128)

typedef short bf16x8 __attribute__((ext_vector_type(8)));
typedef float f32x4 __attribute__((ext_vector_type(4)));
#define MFMA __builtin_amdgcn_mfma_f32_16x16x32_bf16

__device__ __forceinline__ unsigned short f2b(float f) {
    unsigned u = __builtin_bit_cast(unsigned, f);
    unsigned r = (u + 0x7FFFu + ((u >> 16) & 1u)) >> 16;
    return (unsigned short)r;
}
__device__ __forceinline__ float b2f(unsigned short h) {
    unsigned u = ((unsigned)h) << 16;
    return __builtin_bit_cast(float, u);
}

// ---------------- stable compaction (ballot/popcount scan) ----------------
__global__ __launch_bounds__(256)
void k_compact(const float* __restrict__ time_x, const float* __restrict__ value_x,
               const int* __restrict__ mask_x,
               float* __restrict__ compT, float* __restrict__ compU,
               int* __restrict__ compC, int* __restrict__ nvalid)
{
    int b = blockIdx.x, tid = threadIdx.x;
    int lane = tid & 63, w = tid >> 6;
    __shared__ int sW[4];
    __shared__ int s_base;
    if (tid == 0) s_base = 0;
    __syncthreads();
    for (int j0 = 0; j0 < LL; j0 += 256) {
        int j = j0 + tid;
        int m = mask_x[b * LL + j];
        unsigned long long bal = __ballot(m != 0);
        int pre = __popcll(bal & ((1ull << lane) - 1ull));
        if (lane == 0) sW[w] = __popcll(bal);
        __syncthreads();
        int woff = 0;
        for (int i = 0; i < w; ++i) woff += sW[i];
        int tot = sW[0] + sW[1] + sW[2] + sW[3];
        if (m) {
            int pos = s_base + woff + pre;
            compT[b * LL + pos] = time_x[b * SS + j / DD];
            compU[b * LL + pos] = value_x[b * LL + j];
            compC[b * LL + pos] = j % DD;
        }
        __syncthreads();
        if (tid == 0) s_base += tot;
        __syncthreads();
    }
    if (tid == 0) nvalid[b] = s_base;
}

// ---------------- Z init (writes f32 Z, mk, optional bf16 Zb) ----------------
template<int UZ>
__global__ __launch_bounds__(256)
void k_init(const float* __restrict__ Wi, const float* __restrict__ bi,
            const float* __restrict__ compT, const float* __restrict__ compU,
            const int* __restrict__ compC, const int* __restrict__ nvalid,
            float* __restrict__ out, unsigned short* __restrict__ Zb)
{
    int b = blockIdx.y, p0 = blockIdx.x * 8, tid = threadIdx.x;
    float* Z = out;
    float* MK = out + (size_t)BB * LL * LAT;
    int nv = nvalid[b];
    for (int s = 0; s < 2; ++s) {
        int e = s * 256 + tid;
        int r = e >> 6, k2 = (e & 63) * 2;
        int p = p0 + r;
        size_t zi = ((size_t)b * LL + p) * LAT + k2;
        float v0 = 0.f, v1 = 0.f;
        if (p < nv) {
            int c = compC[b * LL + p];
            float t = compT[b * LL + p], u = compU[b * LL + p];
            v0 = fmaxf(Wi[c * LAT + k2]     + t * Wi[41 * LAT + k2]     + u * Wi[42 * LAT + k2]     + bi[k2],     0.f);
            v1 = fmaxf(Wi[c * LAT + k2 + 1] + t * Wi[41 * LAT + k2 + 1] + u * Wi[42 * LAT + k2 + 1] + bi[k2 + 1], 0.f);
        }
        *(float2*)&Z[zi] = make_float2(v0, v1);
        if constexpr (UZ) {
            unsigned short h2[2] = {f2b(v0), f2b(v1)};
            *(unsigned*)&Zb[((size_t)b * LL + p) * LAT + k2] = *(const unsigned*)h2;
        }
        if (k2 == 0) MK[b * LL + p] = (p < nv) ? 1.f : 0.f;
    }
}

// ---------------- prep (all layers): Qh0 (f32+bf16), transposed bf16 weights ----------------
__global__ __launch_bounds__(256)
void k_prep(const float* __restrict__ I, const float* __restrict__ Wq,
            const float* __restrict__ bq,
            const float* __restrict__ Wk, const float* __restrict__ Wv,
            const float* __restrict__ Wo,
            float* __restrict__ Qh0f, unsigned short* __restrict__ Qh0b,
            unsigned short* __restrict__ WkT, unsigned short* __restrict__ WvT,
            unsigned short* __restrict__ WqT, unsigned short* __restrict__ WoT)
{
    __shared__ float srow[128];
    int blk = blockIdx.x, tid = threadIdx.x, l = blockIdx.y;
    const float* Il  = I  + (size_t)l * 16384;
    const float* Wq0 = Wq + (size_t)(l * 2 + 0) * 16384;
    const float* bq0 = bq + (size_t)(l * 2 + 0) * 128;
    const float* Wk0 = Wk + (size_t)(l * 2 + 0) * 16384;
    const float* Wv0 = Wv + (size_t)(l * 2 + 0) * 16384;
    const float* Wq1 = Wq + (size_t)(l * 2 + 1) * 16384;
    const float* Wo1 = Wo + (size_t)(l * 2 + 1) * 16384;
    if (blk < 128) {
        if (tid < 128) srow[tid] = Il[blk * 128 + tid];
        __syncthreads();
        if (tid < 128) {
            float acc = bq0[tid];
            for (int i = 0; i < 128; ++i) acc += srow[i] * Wq0[i * 128 + tid];
            Qh0f[(size_t)l * 16384 + blk * 128 + tid] = acc;
            Qh0b[(size_t)l * 16384 + blk * 128 + tid] = f2b(acc);
        }
    } else {
        const float* src = (blk == 128) ? Wk0 : (blk == 129) ? Wv0 : (blk == 130) ? Wq1 : Wo1;
        unsigned short* dst = (blk == 128) ? WkT : (blk == 129) ? WvT : (blk == 130) ? WqT : WoT;
        dst += (size_t)l * 16384;
        for (int e = tid; e < 16384; e += 256) {
            int i = e >> 7, n = e & 127;
            dst[n * 128 + i] = f2b(src[e]);
        }
    }
}

// ---------------- MAB0 flash: 64-key tiles, no-max exp2 softmax, reg-hoisted ----------------
template<int UZ>
__global__ __launch_bounds__(512, 4)
void k_flash0(const float* __restrict__ Z, const unsigned short* __restrict__ Zb,
              const unsigned short* __restrict__ Qh0b,
              const unsigned short* __restrict__ WkT, const unsigned short* __restrict__ WvT,
              const float* __restrict__ bk0, const float* __restrict__ bv0,
              const int* __restrict__ nvalid, float* __restrict__ ml,
              unsigned short* __restrict__ accp, int ks)
{
    const int chunk = blockIdx.x, b = blockIdx.y;
    const int tid = threadIdx.x, lane = tid & 63, w = tid >> 6;
    const int l16 = lane & 15, g4 = lane >> 4;
    const f32x4 fz = {0.f, 0.f, 0.f, 0.f};

    __shared__ unsigned short sZ[64 * 136];   // [kk][i]
    __shared__ unsigned short sKh[64 * 136];  // [kk][d]
    __shared__ unsigned short sVT[128 * 72];  // [d][kk]
    __shared__ unsigned short sPw[8][16 * 72];// per-wave P scratch [q][key]

    // hoisted invariant fragments (reused every K-tile)
    bf16x8 wkf[4], wvf[4], qf[NH];
    #pragma unroll
    for (int k = 0; k < 4; ++k) {
        wkf[k] = *(const bf16x8*)&WkT[(w * 16 + l16) * 128 + k * 32 + g4 * 8];
        wvf[k] = *(const bf16x8*)&WvT[(w * 16 + l16) * 128 + k * 32 + g4 * 8];
    }
    #pragma unroll
    for (int h = 0; h < NH; ++h)
        qf[h] = *(const bf16x8*)&Qh0b[(w * 16 + l16) * 128 + h * 32 + g4 * 8];

    f32x4 acc[8];
    #pragma unroll
    for (int n = 0; n < 8; ++n) acc[n] = fz;
    float lreg[NH];
    #pragma unroll
    for (int h = 0; h < NH; ++h) lreg[h] = 0.f;

    int nv = nvalid[b];
    int c0 = (int)(((long long)chunk * nv) / ks);
    int c1 = (int)(((long long)(chunk + 1) * nv) / ks);

    float bkd = bk0[w * 16 + l16];
    float bvd = bv0[w * 16 + l16];
    unsigned short* ps = sPw[w];

    const int str = tid >> 3, stc = (tid & 7) * 16;   // 64 rows x 8x16 shorts
    uint4 pz0, pz1;          // UZ=1 prefetch
    float4 pfa[4];           // UZ=0 prefetch
    const uint4 u4z = {0u, 0u, 0u, 0u};
    if (c0 < c1) {
        if constexpr (UZ) {
            const uint4* zsrc = (const uint4*)&Zb[((size_t)b * LL + c0 + str) * LAT + stc];
            pz0 = zsrc[0]; pz1 = zsrc[1];
        } else {
            const float* s = &Z[((size_t)b * LL + c0 + str) * LAT + stc];
            pfa[0] = *(const float4*)(s);     pfa[1] = *(const float4*)(s + 4);
            pfa[2] = *(const float4*)(s + 8); pfa[3] = *(const float4*)(s + 12);
        }
    }

    for (int kt = c0; kt < c1; kt += 64) {
        int nk = min(64, c1 - kt);
        // write staged tile to LDS; rows >= nk zeroed
        if constexpr (UZ) {
            *(uint4*)&sZ[str * 136 + stc]     = (str < nk) ? pz0 : u4z;
            *(uint4*)&sZ[str * 136 + stc + 8] = (str < nk) ? pz1 : u4z;
        } else {
            #pragma unroll
            for (int half = 0; half < 2; ++half) {
                bf16x8 v;
                if (str < nk) {
                    float4 f0 = pfa[half * 2], f1 = pfa[half * 2 + 1];
                    ((unsigned short*)&v)[0] = f2b(f0.x);
                    ((unsigned short*)&v)[1] = f2b(f0.y);
                    ((unsigned short*)&v)[2] = f2b(f0.z);
                    ((unsigned short*)&v)[3] = f2b(f0.w);
                    ((unsigned short*)&v)[4] = f2b(f1.x);
                    ((unsigned short*)&v)[5] = f2b(f1.y);
                    ((unsigned short*)&v)[6] = f2b(f1.z);
                    ((unsigned short*)&v)[7] = f2b(f1.w);
                } else {
                    #pragma unroll
                    for (int j = 0; j < 8; ++j) ((unsigned short*)&v)[j] = 0;
                }
                *(bf16x8*)&sZ[str * 136 + stc + half * 8] = v;
            }
        }
        __syncthreads();
        // prefetch next tile (in flight across compute)
        if (kt + 64 < c1) {
            if constexpr (UZ) {
                const uint4* zsrc = (const uint4*)&Zb[((size_t)b * LL + kt + 64 + str) * LAT + stc];
                pz0 = zsrc[0]; pz1 = zsrc[1];
            } else {
                const float* s = &Z[((size_t)b * LL + kt + 64 + str) * LAT + stc];
                pfa[0] = *(const float4*)(s);     pfa[1] = *(const float4*)(s + 4);
                pfa[2] = *(const float4*)(s + 8); pfa[3] = *(const float4*)(s + 12);
            }
        }
        // K projection: wave w -> d-cols 16w..16w+15
        {
            f32x4 ck[4] = {fz, fz, fz, fz};
            #pragma unroll
            for (int k = 0; k < 4; ++k)
                #pragma unroll
                for (int m = 0; m < 4; ++m) {
                    bf16x8 a = *(const bf16x8*)&sZ[(m * 16 + l16) * 136 + k * 32 + g4 * 8];
                    ck[m] = MFMA(a, wkf[k], ck[m], 0, 0, 0);
                }
            #pragma unroll
            for (int m = 0; m < 4; ++m)
                #pragma unroll
                for (int r = 0; r < 4; ++r)
                    sKh[(m * 16 + g4 * 4 + r) * 136 + w * 16 + l16] = f2b(ck[m][r] + bkd);
        }
        // V projection
        {
            f32x4 cv[4] = {fz, fz, fz, fz};
            #pragma unroll
            for (int k = 0; k < 4; ++k)
                #pragma unroll
                for (int m = 0; m < 4; ++m) {
                    bf16x8 a = *(const bf16x8*)&sZ[(m * 16 + l16) * 136 + k * 32 + g4 * 8];
                    cv[m] = MFMA(a, wvf[k], cv[m], 0, 0, 0);
                }
            #pragma unroll
            for (int m = 0; m < 4; ++m)
                #pragma unroll
                for (int r = 0; r < 4; ++r)
                    sVT[(w * 16 + l16) * 72 + m * 16 + g4 * 4 + r] = f2b(cv[m][r] + bvd);
        }
        __syncthreads();
        // heads: swapped scores, no-max exp2 softmax; lane owns q = w*16+l16
        #pragma unroll
        for (int h = 0; h < NH; ++h) {
            f32x4 s[4];
            #pragma unroll
            for (int mt = 0; mt < 4; ++mt)
                s[mt] = MFMA(*(const bf16x8*)&sKh[(mt * 16 + l16) * 136 + h * 32 + g4 * 8], qf[h], fz, 0, 0, 0);
            float p4[4][4];
            #pragma unroll
            for (int mt = 0; mt < 4; ++mt)
                #pragma unroll
                for (int r = 0; r < 4; ++r)
                    p4[mt][r] = exp2f(s[mt][r] * PSC);
            if (nk < 64) {
                #pragma unroll
                for (int mt = 0; mt < 4; ++mt)
                    #pragma unroll
                    for (int r = 0; r < 4; ++r)
                        if (mt * 16 + g4 * 4 + r >= nk) p4[mt][r] = 0.f;
            }
            float ls = 0.f;
            #pragma unroll
            for (int mt = 0; mt < 4; ++mt)
                #pragma unroll
                for (int r = 0; r < 4; ++r) ls += p4[mt][r];
            ls += __shfl_xor(ls, 16);
            ls += __shfl_xor(ls, 32);
            lreg[h] += ls;
            #pragma unroll
            for (int mt = 0; mt < 4; ++mt) {
                unsigned short pk[4];
                #pragma unroll
                for (int r = 0; r < 4; ++r) pk[r] = f2b(p4[mt][r]);
                *(uint2*)&ps[l16 * 72 + mt * 16 + g4 * 4] = *(const uint2*)pk;
            }
            bf16x8 aP0 = *(const bf16x8*)&ps[l16 * 72 + g4 * 8];
            bf16x8 aP1 = *(const bf16x8*)&ps[l16 * 72 + 32 + g4 * 8];
            #pragma unroll
            for (int nn = 0; nn < 2; ++nn) {
                int d = h * 32 + nn * 16 + l16;
                bf16x8 bV0 = *(const bf16x8*)&sVT[d * 72 + g4 * 8];
                bf16x8 bV1 = *(const bf16x8*)&sVT[d * 72 + 32 + g4 * 8];
                acc[2 * h + nn] = MFMA(aP0, bV0, acc[2 * h + nn], 0, 0, 0);
                acc[2 * h + nn] = MFMA(aP1, bV1, acc[2 * h + nn], 0, 0, 0);
            }
        }
        __syncthreads();
    }
    // epilogue
    size_t mlbase = ((size_t)((size_t)b * ks + chunk) * NH) * 128 * 2;
    if (g4 == 0) {
        int q = w * 16 + l16;
        #pragma unroll
        for (int h = 0; h < NH; ++h) {
            ml[mlbase + ((size_t)h * 128 + q) * 2 + 0] = 0.f;
            ml[mlbase + ((size_t)h * 128 + q) * 2 + 1] = lreg[h];
        }
    }
    size_t abase = ((size_t)((size_t)b * ks + chunk) * 128) * 128;
    #pragma unroll
    for (int n = 0; n < 8; ++n)
        #pragma unroll
        for (int r = 0; r < 4; ++r) {
            int q = w * 16 + g4 * 4 + r;
            int d = n * 16 + l16;
            accp[abase + (size_t)q * 128 + d] = f2b(acc[n][r]);
        }
}

// ---------------- fused: merge MAB0 partials -> O0 -> H -> Kh1b/Vh1Tb ----------------
__global__ __launch_bounds__(128)
void k_post0(const float* __restrict__ ml, const unsigned short* __restrict__ accp,
             const float* __restrict__ Qh0f,
             const float* __restrict__ Wo0, const float* __restrict__ bo0,
             const float* __restrict__ Wk1, const float* __restrict__ bk1,
             const float* __restrict__ Wv1, const float* __restrict__ bv1,
             unsigned short* __restrict__ Kh1b, unsigned short* __restrict__ Vh1Tb, int ks)
{
    int q = blockIdx.x, b = blockIdx.y, d = threadIdx.x, h = d >> 5;
    __shared__ float sx[128], sh2[128];
    float L = 0.f, A = 0.f;
    for (int c = 0; c < ks; ++c) {
        L += ml[((((size_t)b * ks + c) * NH + h) * 128 + q) * 2 + 1];
        A += b2f(accp[(((size_t)b * ks + c) * 128 + q) * 128 + d]);
    }
    float o0 = Qh0f[q * 128 + d] + ((L > 0.f) ? A / L : 0.f);
    sx[d] = o0;
    __syncthreads();
    float acc = bo0[d];
    for (int i = 0; i < 128; ++i) acc += sx[i] * Wo0[i * 128 + d];
    float hv = o0 + fmaxf(acc, 0.f);
    sh2[d] = hv;
    __syncthreads();
    float ak = bk1[d], av = bv1[d];
    for (int i = 0; i < 128; ++i) {
        float x = sh2[i];
        ak += x * Wk1[i * 128 + d];
        av += x * Wv1[i * 128 + d];
    }
    Kh1b[((size_t)b * 128 + q) * 128 + d] = f2b(ak);
    Vh1Tb[((size_t)b * 128 + d) * 128 + q] = f2b(av);
}

// ---------------- MAB1 persistent-chunk (MFMA, no-max exp2 softmax, resident K/V/W) ----------------
template<int UZ>
__global__ __launch_bounds__(256, 2)
void k_mab1(float* __restrict__ Z, unsigned short* __restrict__ Zb,
            const unsigned short* __restrict__ Kh1b,
            const unsigned short* __restrict__ Vh1Tb,
            const unsigned short* __restrict__ WqT, const float* __restrict__ bq1,
            const unsigned short* __restrict__ WoT, const float* __restrict__ bo1,
            const int* __restrict__ nvalid, int writeZb)
{
    const int b = blockIdx.y, chunk = blockIdx.x;
    const int tid = threadIdx.x, lane = tid & 63, w = tid >> 6;   // w = 0..3 = head
    const int l16 = lane & 15, g4 = lane >> 4;
    const int h = w;
    const f32x4 fz = {0.f, 0.f, 0.f, 0.f};

    __shared__ unsigned short sZ[2][32 * 136];    // double-buffered staged Z
    __shared__ unsigned short sQh[32 * 136];      // Qh1 [q][d], becomes O in-place
    __shared__ unsigned short sP[4][16 * 136];    // per-wave P scratch

    const int nv = nvalid[b];
    int c0 = (int)(((long long)chunk * nv) / MAB1_NC);
    int c1 = (int)(((long long)(chunk + 1) * nv) / MAB1_NC);

    // ---- hoist block-invariant operands into registers (read once) ----
    bf16x8 kf[8], vf[2][4], wqf[2][4], wof[2][4];
    #pragma unroll
    for (int mt = 0; mt < 8; ++mt)
        kf[mt] = *(const bf16x8*)&Kh1b[((size_t)b * 128 + mt * 16 + l16) * 128 + h * 32 + g4 * 8];
    #pragma unroll
    for (int nn = 0; nn < 2; ++nn)
        #pragma unroll
        for (int k4 = 0; k4 < 4; ++k4)
            vf[nn][k4] = *(const bf16x8*)&Vh1Tb[((size_t)b * 128 + h * 32 + nn * 16 + l16) * 128 + k4 * 32 + g4 * 8];
    #pragma unroll
    for (int ct = 0; ct < 2; ++ct) {
        int col = w * 32 + ct * 16 + l16;
        #pragma unroll
        for (int k4 = 0; k4 < 4; ++k4) {
            wqf[ct][k4] = *(const bf16x8*)&WqT[col * 128 + k4 * 32 + g4 * 8];
            wof[ct][k4] = *(const bf16x8*)&WoT[col * 128 + k4 * 32 + g4 * 8];
        }
    }
    float bqv[2], bov[2];
    #pragma unroll
    for (int ct = 0; ct < 2; ++ct) {
        bqv[ct] = bq1[w * 32 + ct * 16 + l16];
        bov[ct] = bo1[w * 32 + ct * 16 + l16];
    }

    const int str = tid >> 3, stc = (tid & 7) * 16;   // staging coords (32 rows x 8x16 cols)
    uint4 pz0, pz1;          // UZ=1 prefetch
    float4 pf[4];            // UZ=0 prefetch
    const float4 f4z = {0.f, 0.f, 0.f, 0.f};
    const uint4 u4z = {0u, 0u, 0u, 0u};

    // preload first tile
    if (c0 < c1) {
        bool okr = (c0 + str < c1);
        if constexpr (UZ) {
            if (okr) {
                const uint4* zsrc = (const uint4*)&Zb[((size_t)b * LL + c0 + str) * LAT + stc];
                pz0 = zsrc[0]; pz1 = zsrc[1];
            } else { pz0 = u4z; pz1 = u4z; }
        } else {
            if (okr) {
                const float* zr = &Z[((size_t)b * LL + c0 + str) * LAT + stc];
                pf[0] = *(const float4*)(zr);     pf[1] = *(const float4*)(zr + 4);
                pf[2] = *(const float4*)(zr + 8); pf[3] = *(const float4*)(zr + 12);
            } else { pf[0] = pf[1] = pf[2] = pf[3] = f4z; }
        }
    }

    int cur = 0;
    for (int kt = c0; kt < c1; kt += 32) {
        int nk = min(32, c1 - kt);
        unsigned short* zb_ = sZ[cur];
        // write prefetched regs -> sZ[cur]
        if constexpr (UZ) {
            *(uint4*)&zb_[str * 136 + stc]     = pz0;
            *(uint4*)&zb_[str * 136 + stc + 8] = pz1;
        } else {
            #pragma unroll
            for (int half = 0; half < 2; ++half) {
                float4 f0 = pf[half * 2], f1 = pf[half * 2 + 1];
                bf16x8 v;
                ((unsigned short*)&v)[0] = f2b(f0.x);
                ((unsigned short*)&v)[1] = f2b(f0.y);
                ((unsigned short*)&v)[2] = f2b(f0.z);
                ((unsigned short*)&v)[3] = f2b(f0.w);
                ((unsigned short*)&v)[4] = f2b(f1.x);
                ((unsigned short*)&v)[5] = f2b(f1.y);
                ((unsigned short*)&v)[6] = f2b(f1.z);
                ((unsigned short*)&v)[7] = f2b(f1.w);
                *(bf16x8*)&zb_[str * 136 + stc + half * 8] = v;
            }
        }
        __syncthreads();
        // issue prefetch for next tile (in flight across compute)
        if (kt + 32 < c1) {
            bool okr = (kt + 32 + str < c1);
            if constexpr (UZ) {
                if (okr) {
                    const uint4* zsrc = (const uint4*)&Zb[((size_t)b * LL + kt + 32 + str) * LAT + stc];
                    pz0 = zsrc[0]; pz1 = zsrc[1];
                } else { pz0 = u4z; pz1 = u4z; }
            } else {
                if (okr) {
                    const float* zr = &Z[((size_t)b * LL + kt + 32 + str) * LAT + stc];
                    pf[0] = *(const float4*)(zr);     pf[1] = *(const float4*)(zr + 4);
                    pf[2] = *(const float4*)(zr + 8); pf[3] = *(const float4*)(zr + 12);
                } else { pf[0] = pf[1] = pf[2] = pf[3] = f4z; }
            }
        }
        // ---- Qh1 = Z @ Wq1 + bq1 ; wave w -> cols w*32..+32 (resident weights)
        #pragma unroll
        for (int ct = 0; ct < 2; ++ct) {
            f32x4 c2[2] = {fz, fz};
            int col = w * 32 + ct * 16 + l16;
            #pragma unroll
            for (int k4 = 0; k4 < 4; ++k4) {
                #pragma unroll
                for (int mt = 0; mt < 2; ++mt) {
                    bf16x8 a = *(const bf16x8*)&zb_[(mt * 16 + l16) * 136 + k4 * 32 + g4 * 8];
                    c2[mt] = MFMA(a, wqf[ct][k4], c2[mt], 0, 0, 0);
                }
            }
            #pragma unroll
            for (int mt = 0; mt < 2; ++mt)
                #pragma unroll
                for (int r = 0; r < 4; ++r)
                    sQh[(mt * 16 + g4 * 4 + r) * 136 + col] = f2b(c2[mt][r] + bqv[ct]);
        }
        // no barrier: attn reads only this wave's own sQh cols
        unsigned short* ps = sP[w];
        #pragma unroll
        for (int qt = 0; qt < 2; ++qt) {
            bf16x8 bq8 = *(const bf16x8*)&sQh[(qt * 16 + l16) * 136 + h * 32 + g4 * 8];
            f32x4 s[8];
            #pragma unroll
            for (int mt = 0; mt < 8; ++mt)
                s[mt] = MFMA(kf[mt], bq8, fz, 0, 0, 0);
            float ls = 0.f;
            #pragma unroll
            for (int mt = 0; mt < 8; ++mt)
                #pragma unroll
                for (int r = 0; r < 4; ++r) {
                    float p = exp2f(s[mt][r] * PSC);
                    s[mt][r] = p;
                    ls += p;
                }
            ls += __shfl_xor(ls, 16);
            ls += __shfl_xor(ls, 32);
            float inv = 1.f / ls;
            #pragma unroll
            for (int mt = 0; mt < 8; ++mt) {
                unsigned short p4[4];
                #pragma unroll
                for (int r = 0; r < 4; ++r) p4[r] = f2b(s[mt][r] * inv);
                *(uint2*)&ps[l16 * 136 + mt * 16 + g4 * 4] = *(const uint2*)p4;
            }
            #pragma unroll
            for (int nn = 0; nn < 2; ++nn) {
                f32x4 o = fz;
                #pragma unroll
                for (int k4 = 0; k4 < 4; ++k4) {
                    bf16x8 aP = *(const bf16x8*)&ps[l16 * 136 + k4 * 32 + g4 * 8];
                    o = MFMA(aP, vf[nn][k4], o, 0, 0, 0);
                }
                // O = Qh + attn, in place (own cols, own rows qt*16..)
                int col = h * 32 + nn * 16 + l16;
                #pragma unroll
                for (int r = 0; r < 4; ++r) {
                    int row = qt * 16 + g4 * 4 + r;
                    float val = o[r] + b2f(sQh[row * 136 + col]);
                    sQh[row * 136 + col] = f2b(val);
                }
            }
        }
        __syncthreads();
        // ---- out = Zres + O + relu(O @ Wo1 + bo1); wave w -> cols w*32..+32
        #pragma unroll
        for (int ct = 0; ct < 2; ++ct) {
            f32x4 c2[2] = {fz, fz};
            int col = w * 32 + ct * 16 + l16;
            #pragma unroll
            for (int k4 = 0; k4 < 4; ++k4) {
                #pragma unroll
                for (int mt = 0; mt < 2; ++mt) {
                    bf16x8 a = *(const bf16x8*)&sQh[(mt * 16 + l16) * 136 + k4 * 32 + g4 * 8];
                    c2[mt] = MFMA(a, wof[ct][k4], c2[mt], 0, 0, 0);
                }
            }
            #pragma unroll
            for (int mt = 0; mt < 2; ++mt)
                #pragma unroll
                for (int r = 0; r < 4; ++r) {
                    int row = mt * 16 + g4 * 4 + r;
                    if (row < nk) {
                        size_t zi = ((size_t)b * LL + kt + row) * LAT + col;
                        float val = Z[zi] + b2f(sQh[row * 136 + col]) + fmaxf(c2[mt][r] + bov[ct], 0.f);
                        Z[zi] = val;
                        if constexpr (UZ) {
                            if (writeZb) Zb[((size_t)b * LL + kt + row) * LAT + col] = f2b(val);
                        }
                    }
                }
        }
        cur ^= 1;
    }
}

extern "C" void kernel_launch(void* const* d_in, const int* in_sizes, int n_in,
                              void* d_out, int out_size, void* d_ws, size_t ws_size,
                              hipStream_t stream)
{
    const float* time_x  = (const float*)d_in[0];
    const float* value_x = (const float*)d_in[1];
    const int*   mask_x  = (const int*)d_in[2];
    const float* Wi = (const float*)d_in[3];
    const float* bi = (const float*)d_in[4];
    const float* I  = (const float*)d_in[5];
    const float* Wq = (const float*)d_in[6];
    const float* bq = (const float*)d_in[7];
    const float* Wk = (const float*)d_in[8];
    const float* bk = (const float*)d_in[9];
    const float* Wv = (const float*)d_in[10];
    const float* bv = (const float*)d_in[11];
    const float* Wo = (const float*)d_in[12];
    const float* bo = (const float*)d_in[13];
    float* out = (float*)d_out;

    const size_t BL = (size_t)BB * LL;
    const size_t base_fl = 3 * BL + 64 + (size_t)NL * 16384 + 5 * (size_t)NL * 8192
                         + 2 * (size_t)BB * 8192;
    const size_t zb_fl = BL * 64 + 8192;   // bf16 Z mirror + overrun pad
    auto need = [&](int kss) -> size_t {
        size_t fl = base_fl + (size_t)BB * kss * NH * 256 + (size_t)BB * kss * 8192 + zb_fl;
        return fl * 4;
    };
    int big, ks;
    if (ws_size >= need(32))      { big = 1; ks = 32; }
    else                          { big = 0; ks = 16; }

    float* ws = (float*)d_ws;
    float* compT  = ws;                      ws += BL;
    float* compU  = ws;                      ws += BL;
    int*   compC  = (int*)ws;                ws += BL;
    int*   nvalid = (int*)ws;                ws += 64;
    float* Qh0f   = ws;                      ws += (size_t)NL * 16384;
    unsigned short* Qh0b  = (unsigned short*)ws;  ws += (size_t)NL * 8192;
    unsigned short* WkT   = (unsigned short*)ws;  ws += (size_t)NL * 8192;
    unsigned short* WvT   = (unsigned short*)ws;  ws += (size_t)NL * 8192;
    unsigned short* WqT   = (unsigned short*)ws;  ws += (size_t)NL * 8192;
    unsigned short* WoT   = (unsigned short*)ws;  ws += (size_t)NL * 8192;
    unsigned short* Kh1b  = (unsigned short*)ws;  ws += (size_t)BB * 8192;
    unsigned short* Vh1Tb = (unsigned short*)ws;  ws += (size_t)BB * 8192;
    float* ml     = ws;                      ws += (size_t)BB * ks * NH * 256;
    unsigned short* accp  = (unsigned short*)ws;  ws += (size_t)BB * ks * 8192;
    unsigned short* Zb    = (unsigned short*)ws;  // big path only

    k_compact<<<BB, 256, 0, stream>>>(time_x, value_x, mask_x, compT, compU, compC, nvalid);
    if (big) k_init<1><<<dim3(LL / 8, BB), 256, 0, stream>>>(Wi, bi, compT, compU, compC, nvalid, out, Zb);
    else     k_init<0><<<dim3(LL / 8, BB), 256, 0, stream>>>(Wi, bi, compT, compU, compC, nvalid, out, Zb);
    k_prep<<<dim3(132, NL), 256, 0, stream>>>(I, Wq, bq, Wk, Wv, Wo,
                                              Qh0f, Qh0b, WkT, WvT, WqT, WoT);

    for (int l = 0; l < NL; ++l) {
        const float* Wo0 = Wo + (size_t)(l * 2 + 0) * 16384;
        const float* Wk1 = Wk + (size_t)(l * 2 + 1) * 16384;
        const float* Wv1 = Wv + (size_t)(l * 2 + 1) * 16384;
        const float* bk0 = bk + (l * 2 + 0) * 128;
        const float* bv0 = bv + (l * 2 + 0) * 128;
        const float* bo0 = bo + (l * 2 + 0) * 128;
        const float* bq1 = bq + (l * 2 + 1) * 128;
        const float* bk1 = bk + (l * 2 + 1) * 128;
        const float* bv1 = bv + (l * 2 + 1) * 128;
        const float* bo1 = bo + (l * 2 + 1) * 128;

        if (big)
            k_flash0<1><<<dim3(ks, BB), 512, 0, stream>>>(out, Zb, Qh0b + (size_t)l * 16384,
                                                          WkT + (size_t)l * 16384,
                                                          WvT + (size_t)l * 16384,
                                                          bk0, bv0, nvalid, ml, accp, ks);
        else
            k_flash0<0><<<dim3(ks, BB), 512, 0, stream>>>(out, Zb, Qh0b + (size_t)l * 16384,
                                                          WkT + (size_t)l * 16384,
                                                          WvT + (size_t)l * 16384,
                                                          bk0, bv0, nvalid, ml, accp, ks);
        k_post0<<<dim3(128, BB), 128, 0, stream>>>(ml, accp, Qh0f + (size_t)l * 16384,
                                                   Wo0, bo0, Wk1, bk1, Wv1, bv1, Kh1b, Vh1Tb, ks);
        int wzb = (l < NL - 1) ? 1 : 0;
        if (big)
            k_mab1<1><<<dim3(MAB1_NC, BB), 256, 0, stream>>>(out, Zb, Kh1b, Vh1Tb,
                                                             WqT + (size_t)l * 16384, bq1,
                                                             WoT + (size_t)l * 16384, bo1, nvalid, wzb);
        else
            k_mab1<0><<<dim3(MAB1_NC, BB), 256, 0, stream>>>(out, Zb, Kh1b, Vh1Tb,
                                                             WqT + (size_t)l * 16384, bq1,
                                                             WoT + (size_t)l * 16384, bo1, nvalid, wzb);
    }
}